// Round 1
// baseline (2557.030 us; speedup 1.0000x reference)
//
#include <hip/hip_runtime.h>

typedef unsigned short u16;
typedef unsigned int   u32;
typedef _Float16       f16;
typedef __attribute__((ext_vector_type(4))) _Float16 v4h;
typedef __attribute__((ext_vector_type(8))) _Float16 v8h;   // MFMA A/B frag (4 VGPRs)
typedef __attribute__((ext_vector_type(4))) float    v4f;   // MFMA C/D frag

#define TT 2048
#define BB 8

static __device__ __forceinline__ float sigmoidf_(float x){
    return 1.0f / (1.0f + __expf(-x));
}
static __device__ __forceinline__ float allreduce64(float v){
    #pragma unroll
    for (int off = 32; off > 0; off >>= 1) v += __shfl_xor(v, off, 64);
    return v;
}

// Wave64 sum via DPP (VALU-only). row_shr 1/2/4/8 + row_bcast 15/31; lane 63 total.
static __device__ __forceinline__ float wave_sum64(float x){
    int t;
    t = __builtin_amdgcn_update_dpp(0, __float_as_int(x), 0x111, 0xf, 0xf, true); x += __int_as_float(t);
    t = __builtin_amdgcn_update_dpp(0, __float_as_int(x), 0x112, 0xf, 0xf, true); x += __int_as_float(t);
    t = __builtin_amdgcn_update_dpp(0, __float_as_int(x), 0x114, 0xf, 0xf, true); x += __int_as_float(t);
    t = __builtin_amdgcn_update_dpp(0, __float_as_int(x), 0x118, 0xf, 0xf, true); x += __int_as_float(t);
    t = __builtin_amdgcn_update_dpp(0, __float_as_int(x), 0x142, 0xf, 0xf, true); x += __int_as_float(t);
    t = __builtin_amdgcn_update_dpp(0, __float_as_int(x), 0x143, 0xf, 0xf, true); x += __int_as_float(t);
    return __int_as_float(__builtin_amdgcn_readlane(__float_as_int(x), 63));
}
static __device__ __forceinline__ float rlane(float v, int lane){
    return __int_as_float(__builtin_amdgcn_readlane(__float_as_int(v), lane));
}

// ---------------- diagnostic: fills d_out with sentinel if ws too small ----------------
__global__ __launch_bounds__(256) void sentinel_fill(float* __restrict__ out, int n){
    int i = blockIdx.x * 256 + threadIdx.x;
    if (i < n) out[i] = 12345.0f;
}

// ---------------- LayerNorm: x (16384x1024 f32) -> xn (fp16) ----------------
__global__ __launch_bounds__(256) void ln_kernel(
    const float* __restrict__ x, const float* __restrict__ g,
    const float* __restrict__ bta, f16* __restrict__ xn)
{
    const int row = blockIdx.x;
    const int tid = threadIdx.x;
    const float4 v = ((const float4*)(x + (size_t)row * 1024))[tid];
    float s  = v.x + v.y + v.z + v.w;
    float s2 = v.x*v.x + v.y*v.y + v.z*v.z + v.w*v.w;
    #pragma unroll
    for (int off = 32; off > 0; off >>= 1){
        s  += __shfl_xor(s,  off, 64);
        s2 += __shfl_xor(s2, off, 64);
    }
    __shared__ float rs[4], rq[4];
    const int wv = tid >> 6, lane = tid & 63;
    if (lane == 0){ rs[wv] = s; rq[wv] = s2; }
    __syncthreads();
    s  = rs[0] + rs[1] + rs[2] + rs[3];
    s2 = rq[0] + rq[1] + rq[2] + rq[3];
    const float mu   = s * (1.0f / 1024.0f);
    const float var  = s2 * (1.0f / 1024.0f) - mu * mu;
    const float rstd = rsqrtf(var + 1e-5f);
    const float4 gv = ((const float4*)g)[tid];
    const float4 bv = ((const float4*)bta)[tid];
    v4h o;
    o.x = (f16)((v.x - mu) * rstd * gv.x + bv.x);
    o.y = (f16)((v.y - mu) * rstd * gv.y + bv.y);
    o.z = (f16)((v.z - mu) * rstd * gv.z + bv.z);
    o.w = (f16)((v.w - mu) * rstd * gv.w + bv.w);
    ((v4h*)(xn + (size_t)row * 1024))[tid] = o;
}

// ------- transpose+cast 5 weight mats (1024x1024 f32, [k][n]) -> fp16 [n][k] -------
__global__ __launch_bounds__(256) void transpose5(
    const float* __restrict__ Wq, const float* __restrict__ Wk,
    const float* __restrict__ Wv, const float* __restrict__ Wa,
    const float* __restrict__ Wo, f16* __restrict__ wcat, f16* __restrict__ wot)
{
    __shared__ float tile[32][33];
    const int z = blockIdx.z;
    const float* src = (z==0)?Wq:(z==1)?Wk:(z==2)?Wv:(z==3)?Wa:Wo;
    f16* dst = (z < 4) ? (wcat + (size_t)z * 1024 * 1024) : wot;
    const int bx = blockIdx.x * 32, by = blockIdx.y * 32;
    const int tx = threadIdx.x, ty = threadIdx.y;
    #pragma unroll
    for (int i = 0; i < 4; ++i)
        tile[ty + i*8][tx] = src[(size_t)(by + ty + i*8) * 1024 + bx + tx];
    __syncthreads();
    #pragma unroll
    for (int i = 0; i < 4; ++i)
        dst[(size_t)(bx + ty + i*8) * 1024 + by + tx] = (f16)tile[tx][ty + i*8];
}

// ---------------- fp16 MFMA GEMM, B transposed (N x K). BM=BN=128, BK=64 ----------------
template<int MODE>
__global__ __launch_bounds__(256) void gemm_bt(
    const f16* __restrict__ A, const f16* __restrict__ Bt,
    int M, int N, int K,
    const float* __restrict__ ba, const float* __restrict__ resid,
    float* __restrict__ Cf,
    f16* __restrict__ Qb, f16* __restrict__ Kb,
    f16* __restrict__ Vb, f16* __restrict__ Ab)
{
    __shared__ f16 As[128 * 72];
    __shared__ f16 Bs[128 * 72];
    const int tid = threadIdx.x;
    const int bm = blockIdx.x, bn = blockIdx.y;
    const int wv = tid >> 6, lane = tid & 63;
    const int l15 = lane & 15, quad = lane >> 4;
    const int mb = (wv >> 1) * 64, nb = (wv & 1) * 64;
    v4f acc[4][4];
    const v4f vzero = {0.0f, 0.0f, 0.0f, 0.0f};
    #pragma unroll
    for (int i = 0; i < 4; ++i)
        #pragma unroll
        for (int j = 0; j < 4; ++j) acc[i][j] = vzero;

    const f16* Ag = A  + (size_t)bm * 128 * K;
    const f16* Bg = Bt + (size_t)bn * 128 * K;

    for (int k0 = 0; k0 < K; k0 += 64){
        __syncthreads();
        #pragma unroll
        for (int it = 0; it < 4; ++it){
            const int ch = tid + it * 256;
            const int r = ch >> 3, c = ch & 7;
            const uint4 da = *(const uint4*)(Ag + (size_t)r * K + k0 + c * 8);
            *(uint4*)(&As[r * 72 + c * 8]) = da;
            const uint4 db = *(const uint4*)(Bg + (size_t)r * K + k0 + c * 8);
            *(uint4*)(&Bs[r * 72 + c * 8]) = db;
        }
        __syncthreads();
        #pragma unroll
        for (int kk = 0; kk < 2; ++kk){
            v8h af[4], bfr[4];
            #pragma unroll
            for (int i = 0; i < 4; ++i){
                af[i]  = *(const v8h*)(&As[(mb + i*16 + l15) * 72 + kk*32 + quad*8]);
                bfr[i] = *(const v8h*)(&Bs[(nb + i*16 + l15) * 72 + kk*32 + quad*8]);
            }
            #pragma unroll
            for (int i = 0; i < 4; ++i)
                #pragma unroll
                for (int j = 0; j < 4; ++j)
                    acc[i][j] = __builtin_amdgcn_mfma_f32_16x16x32_f16(af[i], bfr[j], acc[i][j], 0, 0, 0);
        }
    }
    const int seg = (bn * 128) >> 10;
    f16* dst = (seg == 0) ? Qb : (seg == 1) ? Kb : (seg == 2) ? Vb : Ab;
    #pragma unroll
    for (int i = 0; i < 4; ++i){
        #pragma unroll
        for (int j = 0; j < 4; ++j){
            const int col = bn * 128 + nb + j * 16 + l15;
            const int c   = col & 1023;
            #pragma unroll
            for (int r = 0; r < 4; ++r){
                const int row = bm * 128 + mb + i * 16 + quad * 4 + r;
                float val = acc[i][j][r];
                if (MODE == 0){
                    if (seg == 3) val = sigmoidf_(val + ba[c]);
                    dst[(size_t)row * 1024 + c] = (f16)val;
                } else {
                    Cf[(size_t)row * N + col] = val + resid[(size_t)row * N + col];
                }
            }
        }
    }
}

// ---------------- beta: sigmoid(xn @ Wb + bb), stored chain-major [b*16+h][t] ----------------
__global__ __launch_bounds__(256) void beta_kernel(
    const f16* __restrict__ xn, const float* __restrict__ Wb,
    const float* __restrict__ bb, float* __restrict__ betaw)
{
    const int row = blockIdx.x;
    const int b = row >> 11, t = row & 2047;
    const int wv = threadIdx.x >> 6, lane = threadIdx.x & 63;
    const f16* xr = xn + (size_t)row * 1024;
    #pragma unroll
    for (int hh = 0; hh < 4; ++hh){
        const int h = wv * 4 + hh;
        float acc = 0.0f;
        #pragma unroll 4
        for (int k = lane; k < 1024; k += 64)
            acc += (float)xr[k] * Wb[k * 16 + h];
        acc = allreduce64(acc);
        if (lane == 0)
            betaw[((size_t)(b * 16 + h)) * 2048 + t] = sigmoidf_(acc + bb[h]);
    }
}

// ---------------- sequential scan v5: 8 waves (512 thr), 8 rows/thread, fused o ----------------
// Latency-bound fix: 2 waves/SIMD (was 1) for TLP; all per-thread dep chains halve.
// o is fused into phase A via:
//   o[e] = sum_j q[j]*(a[j]*S[j][e])  -  bt*kproj[e]*(ktl.q)  +  bt*v[e]*(kn.q)
// The scalars ktl.q / kn.q are S-independent -> tile preamble (P3).
// Per-step serial work: 32 readlanes + 24 FMA-class ops in phase A + 16 in phase B,
// one barrier, one 8-way LDS partial reduce (serves both kproj and o).
#define SC 16
#define SW 8
__global__ __launch_bounds__(512, 2) void scan_kernel(
    const f16* __restrict__ Qb, const f16* __restrict__ Kb,
    const f16* __restrict__ Vb, const f16* __restrict__ Ab,
    const float* __restrict__ beta, const float* __restrict__ rgm,
    f16* __restrict__ O)
{
    const int chain = blockIdx.x;           // b*16 + h
    const int b = chain >> 4, h = chain & 15;
    const int tid = threadIdx.x;
    const int w = __builtin_amdgcn_readfirstlane(tid) >> 6;   // wave id 0..7
    const int l = tid & 63;
    const int jbase = w << 3;                                  // 8 rows per thread
    const float gm = sigmoidf_(rgm[h]);

    __shared__ f16 tQ[SC * 64], tK[SC * 64], tV[SC * 64], tA[SC * 64];
    __shared__ float betaT[SC];
    __shared__ float rnkT[SC];                 // 1/max(||k_t||,1e-12)
    __shared__ float ktlT[SC * 64];            // k_tilde, f32
    __shared__ float ktlqT[SC], knqT[SC];      // per-step scalars ktl.q, kn.q
    __shared__ float mkP[SC * SW * 64];        // preamble mk partials [t][w][l] (32 KB)
    __shared__ float redK[2][SW * 64];         // kproj partials, dbuf on t&1
    __shared__ float redO[2][SW * 64];         // oq partials, dbuf on t&1

    float m[8], s[8];
    #pragma unroll
    for (int dd = 0; dd < 8; ++dd){
        m[dd] = (jbase + dd == l) ? 1e-6f : 0.0f;  // M0 = EPS*I
        s[dd] = 0.0f;
    }

    const size_t cbase = ((size_t)(b * TT)) * 1024 + h * 64;
    // staging map: 512 chunks of 16B; tensor = tid>>7, step = (tid>>3)&15, chunk = tid&7
    const int tens = tid >> 7, rem = tid & 127;
    const int str = rem >> 3, j4 = rem & 7;
    const f16* sg = (tens == 0) ? Qb : (tens == 1) ? Kb : (tens == 2) ? Vb : Ab;
    f16* sl = (tens == 0) ? tQ : (tens == 1) ? tK : (tens == 2) ? tV : tA;

    for (int t0 = 0; t0 < TT; t0 += SC){
        // ---- stage 16 steps of q/k/v/a (+beta) into LDS ----
        {
            const uint4 d0 = *(const uint4*)(sg + cbase + (size_t)(t0 + str) * 1024 + j4 * 8);
            *(uint4*)(sl + str * 64 + j4 * 8) = d0;
            if (tid < SC) betaT[tid] = beta[(size_t)chain * TT + t0 + tid];
        }
        __syncthreads();   // tiles ready

        // ---- P1: k-norms, 2 steps per wave ----
        #pragma unroll
        for (int rr = 0; rr < 2; ++rr){
            const int t = (w << 1) + rr;
            const float kv = (float)tK[t * 64 + l];
            const float nk = wave_sum64(kv * kv);
            if (l == 0) rnkT[t] = __builtin_amdgcn_rcpf(fmaxf(sqrtf(nk), 1e-12f));
        }
        __syncthreads();   // P1 done

        // ---- P2: bulk M recurrence + mk partials for all 16 steps ----
        #pragma unroll
        for (int t = 0; t < SC; ++t){
            const float knl = (float)tK[t * 64 + l] * rnkT[t];
            float knj2[8];
            #pragma unroll
            for (int dd = 0; dd < 8; ++dd) knj2[dd] = rlane(knl, jbase + dd);
            float mk0 = 0.f, mk1 = 0.f;
            #pragma unroll
            for (int dd = 0; dd < 8; dd += 2){
                m[dd]     = fmaf(gm, m[dd],     knl * knj2[dd]);
                mk0 = fmaf(m[dd], knj2[dd], mk0);
                m[dd + 1] = fmaf(gm, m[dd + 1], knl * knj2[dd + 1]);
                mk1 = fmaf(m[dd + 1], knj2[dd + 1], mk1);
            }
            mkP[(t << 9) + (w << 6) + l] = mk0 + mk1;
        }
        __syncthreads();   // P2 done

        // ---- P3: ktl + per-step scalars (ktl.q, kn.q), 2 steps per wave ----
        #pragma unroll
        for (int rr = 0; rr < 2; ++rr){
            const int t = (w << 1) + rr;
            float mkf = 0.f;
            #pragma unroll
            for (int w2 = 0; w2 < 8; ++w2) mkf += mkP[(t << 9) + (w2 << 6) + l];
            const float nmk = wave_sum64(mkf * mkf);
            const float ktl = mkf * __builtin_amdgcn_rcpf(fmaxf(sqrtf(nmk), 1e-6f));
            ktlT[t * 64 + l] = ktl;
            const float qv  = (float)tQ[t * 64 + l];
            const float knv = (float)tK[t * 64 + l] * rnkT[t];
            const float s1 = wave_sum64(ktl * qv);
            const float s2 = wave_sum64(knv * qv);
            if (l == 0){ ktlqT[t] = s1; knqT[t] = s2; }
        }
        __syncthreads();   // P3 done: ktlT/scalars ready

        // ---- serial S loop: one barrier per step ----
        #pragma unroll 2
        for (int tt = 0; tt < SC; ++tt){
            const float knl  = (float)tK[tt * 64 + l] * rnkT[tt];
            const float avl  = (float)tA[tt * 64 + l];
            const float qvl  = (float)tQ[tt * 64 + l];
            const float vvl  = (float)tV[tt * 64 + l];
            const float ktll = ktlT[tt * 64 + l];
            const float bt   = betaT[tt];

            float knj[8], aj[8], qj[8];
            #pragma unroll
            for (int dd = 0; dd < 8; ++dd){
                knj[dd] = rlane(knl, jbase + dd);
                aj[dd]  = rlane(avl, jbase + dd);
                qj[dd]  = rlane(qvl, jbase + dd);
            }

            // phase A: row-scale + kproj partial + oq partial (fused o)
            float kp0 = 0.f, kp1 = 0.f, oq0 = 0.f, oq1 = 0.f;
            #pragma unroll
            for (int dd = 0; dd < 8; dd += 2){
                s[dd]     *= aj[dd];
                kp0 = fmaf(knj[dd], s[dd], kp0);
                oq0 = fmaf(qj[dd],  s[dd], oq0);
                s[dd + 1] *= aj[dd + 1];
                kp1 = fmaf(knj[dd + 1], s[dd + 1], kp1);
                oq1 = fmaf(qj[dd + 1],  s[dd + 1], oq1);
            }
            redK[tt & 1][(w << 6) + l] = kp0 + kp1;
            redO[tt & 1][(w << 6) + l] = oq0 + oq1;

            // pre-barrier readlanes (independent of kproj)
            float ktlj[8];
            #pragma unroll
            for (int dd = 0; dd < 8; ++dd) ktlj[dd] = rlane(ktll, jbase + dd);

            __syncthreads();                               // the one per-step barrier

            const float* rk = &redK[tt & 1][0];
            const float kproj = ((rk[l] + rk[64 + l]) + (rk[128 + l] + rk[192 + l]))
                              + ((rk[256 + l] + rk[320 + l]) + (rk[384 + l] + rk[448 + l]));
            const float c1 = bt * kproj;
            const float c2 = bt * vvl;

            // phase B: S -= b*ktl(x)kproj ; S += b*kn(x)v   (no o chain here)
            #pragma unroll
            for (int dd = 0; dd < 8; ++dd){
                const float sv = fmaf(-ktlj[dd], c1, s[dd]);
                s[dd] = fmaf(knj[dd], c2, sv);
            }

            // designated wave finalizes o from the same reduce + preamble scalars
            if (w == (tt & 7)){
                const float* ro = &redO[tt & 1][0];
                const float oq = ((ro[l] + ro[64 + l]) + (ro[128 + l] + ro[192 + l]))
                               + ((ro[256 + l] + ro[320 + l]) + (ro[384 + l] + ro[448 + l]));
                const float o = oq - c1 * ktlqT[tt] + bt * knqT[tt] * vvl;
                O[cbase + (size_t)(t0 + tt) * 1024 + l] = (f16)o;
            }
        }
        __syncthreads();   // tile complete: safe to restage
    }
}

// ---------------- workspace layout (bytes), total ~107 MB ----------------
#define OFF_XN    ((size_t)0)                     // 16384*1024 f16 = 32 MB  (later: O)
#define OFF_WCAT  ((size_t)33554432)              // 4*1024*1024 f16 = 8 MB
#define OFF_WOT   ((size_t)41943040)              // 1024*1024 f16  =  2 MB
#define OFF_BETA  ((size_t)44040192)              // 128*2048 f32   =  1 MB
#define OFF_V     ((size_t)45088768)              // 16384*1024 f16 = 32 MB
#define OFF_A     ((size_t)78643200)              // 16384*1024 f16 = 32 MB
#define WS_NEED   ((size_t)112197632)

extern "C" void kernel_launch(void* const* d_in, const int* in_sizes, int n_in,
                              void* d_out, int out_size, void* d_ws, size_t ws_size,
                              hipStream_t stream)
{
    const float* x   = (const float*)d_in[0];
    const float* lng = (const float*)d_in[1];
    const float* lnb = (const float*)d_in[2];
    const float* Wq  = (const float*)d_in[3];
    const float* Wk  = (const float*)d_in[4];
    const float* Wv  = (const float*)d_in[5];
    const float* Wa  = (const float*)d_in[6];
    const float* ba  = (const float*)d_in[7];
    const float* Wb  = (const float*)d_in[8];
    const float* bb  = (const float*)d_in[9];
    const float* rgm = (const float*)d_in[10];
    const float* Wo  = (const float*)d_in[11];
    float* out = (float*)d_out;

    if (ws_size < WS_NEED){
        sentinel_fill<<<(out_size + 255) / 256, 256, 0, stream>>>(out, out_size);
        return;
    }

    char* ws = (char*)d_ws;
    f16*   xn   = (f16*)(ws + OFF_XN);
    f16*   wcat = (f16*)(ws + OFF_WCAT);
    f16*   wot  = (f16*)(ws + OFF_WOT);
    float* betw = (float*)(ws + OFF_BETA);
    f16*   Vbuf = (f16*)(ws + OFF_V);
    f16*   Abuf = (f16*)(ws + OFF_A);
    f16*   Qbuf = (f16*)d_out;                    // 32 MB
    f16*   Kbuf = Qbuf + (size_t)16384 * 1024;    // 32 MB (d_out total = 64 MB)
    f16*   Obuf = xn;                             // reuse xn slot after it's dead

    ln_kernel<<<16384, 256, 0, stream>>>(x, lng, lnb, xn);
    transpose5<<<dim3(32, 32, 5), dim3(32, 8), 0, stream>>>(Wq, Wk, Wv, Wa, Wo, wcat, wot);
    gemm_bt<0><<<dim3(128, 32), 256, 0, stream>>>(xn, wcat, 16384, 4096, 1024,
                                                  ba, nullptr, nullptr, Qbuf, Kbuf, Vbuf, Abuf);
    beta_kernel<<<16384, 256, 0, stream>>>(xn, Wb, bb, betw);
    scan_kernel<<<128, 512, 0, stream>>>(Qbuf, Kbuf, Vbuf, Abuf, betw, rgm, Obuf);
    gemm_bt<1><<<dim3(128, 8), 256, 0, stream>>>(Obuf, wot, 16384, 1024, 1024,
                                                 nullptr, x, out, nullptr, nullptr, nullptr, nullptr);
}

// Round 2
// 2145.963 us; speedup vs baseline: 1.1916x; 1.1916x over previous
//
#include <hip/hip_runtime.h>

typedef unsigned short u16;
typedef unsigned int   u32;
typedef _Float16       f16;
typedef __attribute__((ext_vector_type(4))) _Float16 v4h;
typedef __attribute__((ext_vector_type(8))) _Float16 v8h;   // MFMA A/B frag (4 VGPRs)
typedef __attribute__((ext_vector_type(4))) float    v4f;   // MFMA C/D frag

#define TT 2048
#define BB 8

static __device__ __forceinline__ float sigmoidf_(float x){
    return 1.0f / (1.0f + __expf(-x));
}
static __device__ __forceinline__ float allreduce64(float v){
    #pragma unroll
    for (int off = 32; off > 0; off >>= 1) v += __shfl_xor(v, off, 64);
    return v;
}

// Wave64 sum via DPP (VALU-only). row_shr 1/2/4/8 + row_bcast 15/31; lane 63 total.
static __device__ __forceinline__ float wave_sum64(float x){
    int t;
    t = __builtin_amdgcn_update_dpp(0, __float_as_int(x), 0x111, 0xf, 0xf, true); x += __int_as_float(t);
    t = __builtin_amdgcn_update_dpp(0, __float_as_int(x), 0x112, 0xf, 0xf, true); x += __int_as_float(t);
    t = __builtin_amdgcn_update_dpp(0, __float_as_int(x), 0x114, 0xf, 0xf, true); x += __int_as_float(t);
    t = __builtin_amdgcn_update_dpp(0, __float_as_int(x), 0x118, 0xf, 0xf, true); x += __int_as_float(t);
    t = __builtin_amdgcn_update_dpp(0, __float_as_int(x), 0x142, 0xf, 0xf, true); x += __int_as_float(t);
    t = __builtin_amdgcn_update_dpp(0, __float_as_int(x), 0x143, 0xf, 0xf, true); x += __int_as_float(t);
    return __int_as_float(__builtin_amdgcn_readlane(__float_as_int(x), 63));
}
static __device__ __forceinline__ float rlane(float v, int lane){
    return __int_as_float(__builtin_amdgcn_readlane(__float_as_int(v), lane));
}

// ---------------- diagnostic: fills d_out with sentinel if ws too small ----------------
__global__ __launch_bounds__(256) void sentinel_fill(float* __restrict__ out, int n){
    int i = blockIdx.x * 256 + threadIdx.x;
    if (i < n) out[i] = 12345.0f;
}

// ---------------- LayerNorm: x (16384x1024 f32) -> xn (fp16) ----------------
__global__ __launch_bounds__(256) void ln_kernel(
    const float* __restrict__ x, const float* __restrict__ g,
    const float* __restrict__ bta, f16* __restrict__ xn)
{
    const int row = blockIdx.x;
    const int tid = threadIdx.x;
    const float4 v = ((const float4*)(x + (size_t)row * 1024))[tid];
    float s  = v.x + v.y + v.z + v.w;
    float s2 = v.x*v.x + v.y*v.y + v.z*v.z + v.w*v.w;
    #pragma unroll
    for (int off = 32; off > 0; off >>= 1){
        s  += __shfl_xor(s,  off, 64);
        s2 += __shfl_xor(s2, off, 64);
    }
    __shared__ float rs[4], rq[4];
    const int wv = tid >> 6, lane = tid & 63;
    if (lane == 0){ rs[wv] = s; rq[wv] = s2; }
    __syncthreads();
    s  = rs[0] + rs[1] + rs[2] + rs[3];
    s2 = rq[0] + rq[1] + rq[2] + rq[3];
    const float mu   = s * (1.0f / 1024.0f);
    const float var  = s2 * (1.0f / 1024.0f) - mu * mu;
    const float rstd = rsqrtf(var + 1e-5f);
    const float4 gv = ((const float4*)g)[tid];
    const float4 bv = ((const float4*)bta)[tid];
    v4h o;
    o.x = (f16)((v.x - mu) * rstd * gv.x + bv.x);
    o.y = (f16)((v.y - mu) * rstd * gv.y + bv.y);
    o.z = (f16)((v.z - mu) * rstd * gv.z + bv.z);
    o.w = (f16)((v.w - mu) * rstd * gv.w + bv.w);
    ((v4h*)(xn + (size_t)row * 1024))[tid] = o;
}

// ------- transpose+cast 5 weight mats (1024x1024 f32, [k][n]) -> fp16 [n][k] -------
__global__ __launch_bounds__(256) void transpose5(
    const float* __restrict__ Wq, const float* __restrict__ Wk,
    const float* __restrict__ Wv, const float* __restrict__ Wa,
    const float* __restrict__ Wo, f16* __restrict__ wcat, f16* __restrict__ wot)
{
    __shared__ float tile[32][33];
    const int z = blockIdx.z;
    const float* src = (z==0)?Wq:(z==1)?Wk:(z==2)?Wv:(z==3)?Wa:Wo;
    f16* dst = (z < 4) ? (wcat + (size_t)z * 1024 * 1024) : wot;
    const int bx = blockIdx.x * 32, by = blockIdx.y * 32;
    const int tx = threadIdx.x, ty = threadIdx.y;
    #pragma unroll
    for (int i = 0; i < 4; ++i)
        tile[ty + i*8][tx] = src[(size_t)(by + ty + i*8) * 1024 + bx + tx];
    __syncthreads();
    #pragma unroll
    for (int i = 0; i < 4; ++i)
        dst[(size_t)(bx + ty + i*8) * 1024 + by + tx] = (f16)tile[tx][ty + i*8];
}

// ---------------- fp16 MFMA GEMM, B transposed (N x K). BM=BN=128, BK=64 ----------------
template<int MODE>
__global__ __launch_bounds__(256) void gemm_bt(
    const f16* __restrict__ A, const f16* __restrict__ Bt,
    int M, int N, int K,
    const float* __restrict__ ba, const float* __restrict__ resid,
    float* __restrict__ Cf,
    f16* __restrict__ Qb, f16* __restrict__ Kb,
    f16* __restrict__ Vb, f16* __restrict__ Ab)
{
    __shared__ f16 As[128 * 72];
    __shared__ f16 Bs[128 * 72];
    const int tid = threadIdx.x;
    const int bm = blockIdx.x, bn = blockIdx.y;
    const int wv = tid >> 6, lane = tid & 63;
    const int l15 = lane & 15, quad = lane >> 4;
    const int mb = (wv >> 1) * 64, nb = (wv & 1) * 64;
    v4f acc[4][4];
    const v4f vzero = {0.0f, 0.0f, 0.0f, 0.0f};
    #pragma unroll
    for (int i = 0; i < 4; ++i)
        #pragma unroll
        for (int j = 0; j < 4; ++j) acc[i][j] = vzero;

    const f16* Ag = A  + (size_t)bm * 128 * K;
    const f16* Bg = Bt + (size_t)bn * 128 * K;

    for (int k0 = 0; k0 < K; k0 += 64){
        __syncthreads();
        #pragma unroll
        for (int it = 0; it < 4; ++it){
            const int ch = tid + it * 256;
            const int r = ch >> 3, c = ch & 7;
            const uint4 da = *(const uint4*)(Ag + (size_t)r * K + k0 + c * 8);
            *(uint4*)(&As[r * 72 + c * 8]) = da;
            const uint4 db = *(const uint4*)(Bg + (size_t)r * K + k0 + c * 8);
            *(uint4*)(&Bs[r * 72 + c * 8]) = db;
        }
        __syncthreads();
        #pragma unroll
        for (int kk = 0; kk < 2; ++kk){
            v8h af[4], bfr[4];
            #pragma unroll
            for (int i = 0; i < 4; ++i){
                af[i]  = *(const v8h*)(&As[(mb + i*16 + l15) * 72 + kk*32 + quad*8]);
                bfr[i] = *(const v8h*)(&Bs[(nb + i*16 + l15) * 72 + kk*32 + quad*8]);
            }
            #pragma unroll
            for (int i = 0; i < 4; ++i)
                #pragma unroll
                for (int j = 0; j < 4; ++j)
                    acc[i][j] = __builtin_amdgcn_mfma_f32_16x16x32_f16(af[i], bfr[j], acc[i][j], 0, 0, 0);
        }
    }
    const int seg = (bn * 128) >> 10;
    f16* dst = (seg == 0) ? Qb : (seg == 1) ? Kb : (seg == 2) ? Vb : Ab;
    #pragma unroll
    for (int i = 0; i < 4; ++i){
        #pragma unroll
        for (int j = 0; j < 4; ++j){
            const int col = bn * 128 + nb + j * 16 + l15;
            const int c   = col & 1023;
            #pragma unroll
            for (int r = 0; r < 4; ++r){
                const int row = bm * 128 + mb + i * 16 + quad * 4 + r;
                float val = acc[i][j][r];
                if (MODE == 0){
                    if (seg == 3) val = sigmoidf_(val + ba[c]);
                    dst[(size_t)row * 1024 + c] = (f16)val;
                } else {
                    Cf[(size_t)row * N + col] = val + resid[(size_t)row * N + col];
                }
            }
        }
    }
}

// ---------------- beta: sigmoid(xn @ Wb + bb), stored chain-major [b*16+h][t] ----------------
__global__ __launch_bounds__(256) void beta_kernel(
    const f16* __restrict__ xn, const float* __restrict__ Wb,
    const float* __restrict__ bb, float* __restrict__ betaw)
{
    const int row = blockIdx.x;
    const int b = row >> 11, t = row & 2047;
    const int wv = threadIdx.x >> 6, lane = threadIdx.x & 63;
    const f16* xr = xn + (size_t)row * 1024;
    #pragma unroll
    for (int hh = 0; hh < 4; ++hh){
        const int h = wv * 4 + hh;
        float acc = 0.0f;
        #pragma unroll 4
        for (int k = lane; k < 1024; k += 64)
            acc += (float)xr[k] * Wb[k * 16 + h];
        acc = allreduce64(acc);
        if (lane == 0)
            betaw[((size_t)(b * 16 + h)) * 2048 + t] = sigmoidf_(acc + bb[h]);
    }
}

// ---------------- scan v6: per-tile WY reformulation (no per-step sync) ----------------
// Gauge: S_t = diag(G_t) Z_t  with G_t = within-tile cumprod(a). Then
//   Z_t = Z_{t-1} - u_t (p_t^T Z_{t-1}) + w_t v_t^T,
//   p=kn*G, u=beta*ktl/G, w=beta*kn/G, q'=q*G (all S-independent).
// WY over a 16-step tile:  h_t := p_t^T Z_{t-1}
//   (I + SL(P U^T)) H = P Z0 + SL(P W^T) V        (16x16 fwd-subst, 1 wave)
//   O   = Q' Z0 + L(Q' W^T) V - L(Q' U^T) H       (L incl. diagonal)
//   Z_L = Z0 + W^T V - U^T H ;  Z0_next = diag(G_L) Z_L
// Replaces 16 per-step barriers/LDS-roundtrips with 9 per-tile barriers of
// dense parallel f32 VALU work. M/ktl preamble (P1-P3) verbatim from v5 (verified).
#define SC 16
__global__ __launch_bounds__(512, 2) void scan_kernel(
    const f16* __restrict__ Qb, const f16* __restrict__ Kb,
    const f16* __restrict__ Vb, const f16* __restrict__ Ab,
    const float* __restrict__ beta, const float* __restrict__ rgm,
    f16* __restrict__ O)
{
    const int chain = blockIdx.x;           // b*16 + h
    const int b = chain >> 4, h = chain & 15;
    const int tid = threadIdx.x;
    const int wid = __builtin_amdgcn_readfirstlane(tid) >> 6;  // wave id 0..7
    const int l = tid & 63;
    const int jbase = wid << 3;                                // 8 M-rows per thread
    const float gm = sigmoidf_(rgm[h]);

    __shared__ f16 tQ[SC * 64], tK[SC * 64], tV[SC * 64], tA[SC * 64];
    __shared__ float betaT[SC], rnkT[SC];
    __shared__ float ktlT[SC * 64];            // k_tilde (f32)
    __shared__ float mkP[SC * 8 * 64];         // M-recurrence partials (32 KB)
    __shared__ float Zs[64 * 64];              // gauge state Z (f32, persistent)
    __shared__ float Pt[SC * 68], Ut[SC * 68], Wt[SC * 68], Qt[SC * 68]; // padded
    __shared__ float Vf[SC * 64];              // V in f32
    __shared__ float Gc[SC * 64];              // cumprod gates
    __shared__ float Hs[SC * 64];              // RHS -> solved H
    __shared__ float Ob2[SC * 64];             // Q' Z0 partial of O
    __shared__ float Cm[4][SC * SC];           // 0:SL(PW^T) 1:SL(PU^T) 2:L(Q'W^T) 3:L(Q'U^T)

    float m[8];
    #pragma unroll
    for (int dd = 0; dd < 8; ++dd)
        m[dd] = (jbase + dd == l) ? 1e-6f : 0.0f;   // M0 = EPS*I

    #pragma unroll
    for (int r = 0; r < 8; ++r) Zs[r * 512 + tid] = 0.0f;   // S0 = 0

    const size_t cbase = ((size_t)(b * TT)) * 1024 + h * 64;
    const int tens = tid >> 7, rem = tid & 127;
    const int str = rem >> 3, j4 = rem & 7;
    const f16* sg = (tens == 0) ? Qb : (tens == 1) ? Kb : (tens == 2) ? Vb : Ab;
    f16* sl = (tens == 0) ? tQ : (tens == 1) ? tK : (tens == 2) ? tV : tA;

    for (int t0 = 0; t0 < TT; t0 += SC){
        // ---- stage 16 steps of q/k/v/a (+beta) ----
        {
            const uint4 d0 = *(const uint4*)(sg + cbase + (size_t)(t0 + str) * 1024 + j4 * 8);
            *(uint4*)(sl + str * 64 + j4 * 8) = d0;
            if (tid < SC) betaT[tid] = beta[(size_t)chain * TT + t0 + tid];
        }
        __syncthreads();   // B0

        // ---- P1: k-norms (2/wave) + G cumprod (wave 7) + V->f32 (all) ----
        {
            #pragma unroll
            for (int rr = 0; rr < 2; ++rr){
                const int t = (wid << 1) + rr;
                const float kv = (float)tK[t * 64 + l];
                const float nk = wave_sum64(kv * kv);
                if (l == 0) rnkT[t] = __builtin_amdgcn_rcpf(fmaxf(sqrtf(nk), 1e-12f));
            }
            Vf[tid]       = (float)tV[tid];
            Vf[tid + 512] = (float)tV[tid + 512];
            if (wid == 7){
                float g = 1.0f;
                #pragma unroll
                for (int t = 0; t < SC; ++t){
                    g *= (float)tA[t * 64 + l];
                    Gc[t * 64 + l] = g;
                }
            }
        }
        __syncthreads();   // B1

        // ---- P2: bulk M recurrence + mk partials (verbatim v5) ----
        #pragma unroll
        for (int t = 0; t < SC; ++t){
            const float knl = (float)tK[t * 64 + l] * rnkT[t];
            float knj2[8];
            #pragma unroll
            for (int dd = 0; dd < 8; ++dd) knj2[dd] = rlane(knl, jbase + dd);
            float mk0 = 0.f, mk1 = 0.f;
            #pragma unroll
            for (int dd = 0; dd < 8; dd += 2){
                m[dd]     = fmaf(gm, m[dd],     knl * knj2[dd]);
                mk0 = fmaf(m[dd], knj2[dd], mk0);
                m[dd + 1] = fmaf(gm, m[dd + 1], knl * knj2[dd + 1]);
                mk1 = fmaf(m[dd + 1], knj2[dd + 1], mk1);
            }
            mkP[(t << 9) + (wid << 6) + l] = mk0 + mk1;
        }
        __syncthreads();   // B2

        // ---- P3: reduce mk + normalize ktl (2/wave) ----
        #pragma unroll
        for (int rr = 0; rr < 2; ++rr){
            const int t = (wid << 1) + rr;
            float mkf = 0.f;
            #pragma unroll
            for (int w2 = 0; w2 < 8; ++w2) mkf += mkP[(t << 9) + (w2 << 6) + l];
            const float nmk = wave_sum64(mkf * mkf);
            ktlT[t * 64 + l] = mkf * __builtin_amdgcn_rcpf(fmaxf(sqrtf(nmk), 1e-6f));
        }
        __syncthreads();   // B3

        // ---- P4: gauge tables P,U,W,Q' (2 elems/thread) ----
        #pragma unroll
        for (int half = 0; half < 2; ++half){
            const int idx = tid + half * 512;
            const int t = idx >> 6, d = idx & 63;
            const float g    = Gc[t * 64 + d];
            const float invg = 1.0f / g;
            const float kn   = (float)tK[t * 64 + d] * rnkT[t];
            const float bt   = betaT[t];
            Pt[t * 68 + d] = kn * g;
            Ut[t * 68 + d] = bt * ktlT[t * 64 + d] * invg;
            Wt[t * 68 + d] = bt * kn * invg;
            Qt[t * 68 + d] = (float)tQ[t * 64 + d] * g;
        }
        __syncthreads();   // B4

        // ---- P5: 4x 16x16 pair matrices  +  W4: R = [P;Q'] Z0 ----
        #pragma unroll
        for (int half = 0; half < 2; ++half){
            const int ent = tid + half * 512;
            const int mm = ent >> 8, t = (ent >> 4) & 15, i = ent & 15;
            const float* Arow = (mm < 2) ? &Pt[t * 68] : &Qt[t * 68];
            const float* Brow = ((mm & 1) == 0) ? &Wt[i * 68] : &Ut[i * 68];
            float dot = 0.f;
            #pragma unroll
            for (int k4 = 0; k4 < 16; ++k4){
                const float4 a4 = *(const float4*)(Arow + k4 * 4);
                const float4 b4 = *(const float4*)(Brow + k4 * 4);
                dot = fmaf(a4.x, b4.x, fmaf(a4.y, b4.y, fmaf(a4.z, b4.z, fmaf(a4.w, b4.w, dot))));
            }
            const bool keep = (mm < 2) ? (i < t) : (i <= t);
            Cm[mm][t * 16 + i] = keep ? dot : 0.0f;
        }
        {   // W4: rows wid*4..wid*4+3 of [P(16);Q'(16)] x Z0 -> Hs / Ob2
            const float* Abase = (wid < 4) ? Pt : Qt;
            const int rr0 = (wid & 3) * 4;
            float a0 = 0.f, a1 = 0.f, a2 = 0.f, a3 = 0.f;
            #pragma unroll
            for (int k4 = 0; k4 < 16; ++k4){
                const float4 r0 = *(const float4*)(Abase + (rr0    ) * 68 + k4 * 4);
                const float4 r1 = *(const float4*)(Abase + (rr0 + 1) * 68 + k4 * 4);
                const float4 r2 = *(const float4*)(Abase + (rr0 + 2) * 68 + k4 * 4);
                const float4 r3 = *(const float4*)(Abase + (rr0 + 3) * 68 + k4 * 4);
                const float z0 = Zs[(k4 * 4    ) * 64 + l];
                const float z1 = Zs[(k4 * 4 + 1) * 64 + l];
                const float z2 = Zs[(k4 * 4 + 2) * 64 + l];
                const float z3 = Zs[(k4 * 4 + 3) * 64 + l];
                a0 = fmaf(r0.x, z0, fmaf(r0.y, z1, fmaf(r0.z, z2, fmaf(r0.w, z3, a0))));
                a1 = fmaf(r1.x, z0, fmaf(r1.y, z1, fmaf(r1.z, z2, fmaf(r1.w, z3, a1))));
                a2 = fmaf(r2.x, z0, fmaf(r2.y, z1, fmaf(r2.z, z2, fmaf(r2.w, z3, a2))));
                a3 = fmaf(r3.x, z0, fmaf(r3.y, z1, fmaf(r3.z, z2, fmaf(r3.w, z3, a3))));
            }
            float* Rdst = (wid < 4) ? Hs : Ob2;
            Rdst[(rr0    ) * 64 + l] = a0;
            Rdst[(rr0 + 1) * 64 + l] = a1;
            Rdst[(rr0 + 2) * 64 + l] = a2;
            Rdst[(rr0 + 3) * 64 + l] = a3;
        }
        __syncthreads();   // B5

        // ---- W5a: Hs += SL(PW^T) V  (masked coeffs already zeroed) ----
        #pragma unroll
        for (int tt2 = 0; tt2 < 2; ++tt2){
            const int t = (wid << 1) + tt2;
            float acc = 0.f;
            #pragma unroll
            for (int i = 0; i < SC; ++i)
                acc = fmaf(Cm[0][t * 16 + i], Vf[i * 64 + l], acc);
            Hs[t * 64 + l] += acc;
        }
        __syncthreads();   // B6

        // ---- solve (I + SL(PU^T)) H = RHS : wave 0, fwd substitution ----
        if (wid == 0){
            float hreg[SC];
            #pragma unroll
            for (int t = 0; t < SC; ++t){
                float x = Hs[t * 64 + l];
                #pragma unroll
                for (int i = 0; i < SC; ++i)
                    if (i < t) x = fmaf(-Cm[1][t * 16 + i], hreg[i], x);
                hreg[t] = x;
                Hs[t * 64 + l] = x;
            }
        }
        __syncthreads();   // B7

        // ---- W6: O out  +  W7: Z commit ----
        {
            #pragma unroll
            for (int tt2 = 0; tt2 < 2; ++tt2){
                const int t = (wid << 1) + tt2;
                float o = Ob2[t * 64 + l];
                #pragma unroll
                for (int i = 0; i < SC; ++i){
                    o = fmaf(Cm[2][t * 16 + i],  Vf[i * 64 + l], o);
                    o = fmaf(-Cm[3][t * 16 + i], Hs[i * 64 + l], o);
                }
                O[cbase + (size_t)(t0 + t) * 1024 + l] = (f16)o;
            }
            // Z: rows wid*8..wid*8+7
            const int d0 = wid * 8;
            float za[8];
            #pragma unroll
            for (int r = 0; r < 8; ++r) za[r] = Zs[(d0 + r) * 64 + l];
            #pragma unroll
            for (int i = 0; i < SC; ++i){
                const float4 w0 = *(const float4*)(&Wt[i * 68 + d0]);
                const float4 w1 = *(const float4*)(&Wt[i * 68 + d0 + 4]);
                const float4 u0 = *(const float4*)(&Ut[i * 68 + d0]);
                const float4 u1 = *(const float4*)(&Ut[i * 68 + d0 + 4]);
                const float vv = Vf[i * 64 + l];
                const float hh = Hs[i * 64 + l];
                za[0] = fmaf(w0.x, vv, fmaf(-u0.x, hh, za[0]));
                za[1] = fmaf(w0.y, vv, fmaf(-u0.y, hh, za[1]));
                za[2] = fmaf(w0.z, vv, fmaf(-u0.z, hh, za[2]));
                za[3] = fmaf(w0.w, vv, fmaf(-u0.w, hh, za[3]));
                za[4] = fmaf(w1.x, vv, fmaf(-u1.x, hh, za[4]));
                za[5] = fmaf(w1.y, vv, fmaf(-u1.y, hh, za[5]));
                za[6] = fmaf(w1.z, vv, fmaf(-u1.z, hh, za[6]));
                za[7] = fmaf(w1.w, vv, fmaf(-u1.w, hh, za[7]));
            }
            #pragma unroll
            for (int r = 0; r < 8; ++r)
                Zs[(d0 + r) * 64 + l] = Gc[15 * 64 + d0 + r] * za[r];
        }
        __syncthreads();   // B8 (next stage overwrites tQ/tK/tV/tA)
    }
}

// ---------------- workspace layout (bytes), total ~107 MB ----------------
#define OFF_XN    ((size_t)0)                     // 16384*1024 f16 = 32 MB  (later: O)
#define OFF_WCAT  ((size_t)33554432)              // 4*1024*1024 f16 = 8 MB
#define OFF_WOT   ((size_t)41943040)              // 1024*1024 f16  =  2 MB
#define OFF_BETA  ((size_t)44040192)              // 128*2048 f32   =  1 MB
#define OFF_V     ((size_t)45088768)              // 16384*1024 f16 = 32 MB
#define OFF_A     ((size_t)78643200)              // 16384*1024 f16 = 32 MB
#define WS_NEED   ((size_t)112197632)

extern "C" void kernel_launch(void* const* d_in, const int* in_sizes, int n_in,
                              void* d_out, int out_size, void* d_ws, size_t ws_size,
                              hipStream_t stream)
{
    const float* x   = (const float*)d_in[0];
    const float* lng = (const float*)d_in[1];
    const float* lnb = (const float*)d_in[2];
    const float* Wq  = (const float*)d_in[3];
    const float* Wk  = (const float*)d_in[4];
    const float* Wv  = (const float*)d_in[5];
    const float* Wa  = (const float*)d_in[6];
    const float* ba  = (const float*)d_in[7];
    const float* Wb  = (const float*)d_in[8];
    const float* bb  = (const float*)d_in[9];
    const float* rgm = (const float*)d_in[10];
    const float* Wo  = (const float*)d_in[11];
    float* out = (float*)d_out;

    if (ws_size < WS_NEED){
        sentinel_fill<<<(out_size + 255) / 256, 256, 0, stream>>>(out, out_size);
        return;
    }

    char* ws = (char*)d_ws;
    f16*   xn   = (f16*)(ws + OFF_XN);
    f16*   wcat = (f16*)(ws + OFF_WCAT);
    f16*   wot  = (f16*)(ws + OFF_WOT);
    float* betw = (float*)(ws + OFF_BETA);
    f16*   Vbuf = (f16*)(ws + OFF_V);
    f16*   Abuf = (f16*)(ws + OFF_A);
    f16*   Qbuf = (f16*)d_out;                    // 32 MB
    f16*   Kbuf = Qbuf + (size_t)16384 * 1024;    // 32 MB (d_out total = 64 MB)
    f16*   Obuf = xn;                             // reuse xn slot after it's dead

    ln_kernel<<<16384, 256, 0, stream>>>(x, lng, lnb, xn);
    transpose5<<<dim3(32, 32, 5), dim3(32, 8), 0, stream>>>(Wq, Wk, Wv, Wa, Wo, wcat, wot);
    gemm_bt<0><<<dim3(128, 32), 256, 0, stream>>>(xn, wcat, 16384, 4096, 1024,
                                                  ba, nullptr, nullptr, Qbuf, Kbuf, Vbuf, Abuf);
    beta_kernel<<<16384, 256, 0, stream>>>(xn, Wb, bb, betw);
    scan_kernel<<<128, 512, 0, stream>>>(Qbuf, Kbuf, Vbuf, Abuf, betw, rgm, Obuf);
    gemm_bt<1><<<dim3(128, 8), 256, 0, stream>>>(Obuf, wot, 16384, 1024, 1024,
                                                 nullptr, x, out, nullptr, nullptr, nullptr, nullptr);
}

// Round 3
// 1724.919 us; speedup vs baseline: 1.4824x; 1.2441x over previous
//
#include <hip/hip_runtime.h>

typedef unsigned short u16;
typedef unsigned int   u32;
typedef _Float16       f16;
typedef __attribute__((ext_vector_type(4))) _Float16 v4h;
typedef __attribute__((ext_vector_type(8))) _Float16 v8h;   // MFMA A/B frag (4 VGPRs)
typedef __attribute__((ext_vector_type(4))) float    v4f;   // MFMA C/D frag

#define TT 2048
#define BB 8

static __device__ __forceinline__ float sigmoidf_(float x){
    return 1.0f / (1.0f + __expf(-x));
}
static __device__ __forceinline__ float allreduce64(float v){
    #pragma unroll
    for (int off = 32; off > 0; off >>= 1) v += __shfl_xor(v, off, 64);
    return v;
}

// Wave64 sum via DPP (VALU-only). row_shr 1/2/4/8 + row_bcast 15/31; lane 63 total.
static __device__ __forceinline__ float wave_sum64(float x){
    int t;
    t = __builtin_amdgcn_update_dpp(0, __float_as_int(x), 0x111, 0xf, 0xf, true); x += __int_as_float(t);
    t = __builtin_amdgcn_update_dpp(0, __float_as_int(x), 0x112, 0xf, 0xf, true); x += __int_as_float(t);
    t = __builtin_amdgcn_update_dpp(0, __float_as_int(x), 0x114, 0xf, 0xf, true); x += __int_as_float(t);
    t = __builtin_amdgcn_update_dpp(0, __float_as_int(x), 0x118, 0xf, 0xf, true); x += __int_as_float(t);
    t = __builtin_amdgcn_update_dpp(0, __float_as_int(x), 0x142, 0xf, 0xf, true); x += __int_as_float(t);
    t = __builtin_amdgcn_update_dpp(0, __float_as_int(x), 0x143, 0xf, 0xf, true); x += __int_as_float(t);
    return __int_as_float(__builtin_amdgcn_readlane(__float_as_int(x), 63));
}
static __device__ __forceinline__ float rlane(float v, int lane){
    return __int_as_float(__builtin_amdgcn_readlane(__float_as_int(v), lane));
}

// ---------------- diagnostic: fills d_out with sentinel if ws too small ----------------
__global__ __launch_bounds__(256) void sentinel_fill(float* __restrict__ out, int n){
    int i = blockIdx.x * 256 + threadIdx.x;
    if (i < n) out[i] = 12345.0f;
}

// ---------------- LayerNorm: x (16384x1024 f32) -> xn (fp16) ----------------
__global__ __launch_bounds__(256) void ln_kernel(
    const float* __restrict__ x, const float* __restrict__ g,
    const float* __restrict__ bta, f16* __restrict__ xn)
{
    const int row = blockIdx.x;
    const int tid = threadIdx.x;
    const float4 v = ((const float4*)(x + (size_t)row * 1024))[tid];
    float s  = v.x + v.y + v.z + v.w;
    float s2 = v.x*v.x + v.y*v.y + v.z*v.z + v.w*v.w;
    #pragma unroll
    for (int off = 32; off > 0; off >>= 1){
        s  += __shfl_xor(s,  off, 64);
        s2 += __shfl_xor(s2, off, 64);
    }
    __shared__ float rs[4], rq[4];
    const int wv = tid >> 6, lane = tid & 63;
    if (lane == 0){ rs[wv] = s; rq[wv] = s2; }
    __syncthreads();
    s  = rs[0] + rs[1] + rs[2] + rs[3];
    s2 = rq[0] + rq[1] + rq[2] + rq[3];
    const float mu   = s * (1.0f / 1024.0f);
    const float var  = s2 * (1.0f / 1024.0f) - mu * mu;
    const float rstd = rsqrtf(var + 1e-5f);
    const float4 gv = ((const float4*)g)[tid];
    const float4 bv = ((const float4*)bta)[tid];
    v4h o;
    o.x = (f16)((v.x - mu) * rstd * gv.x + bv.x);
    o.y = (f16)((v.y - mu) * rstd * gv.y + bv.y);
    o.z = (f16)((v.z - mu) * rstd * gv.z + bv.z);
    o.w = (f16)((v.w - mu) * rstd * gv.w + bv.w);
    ((v4h*)(xn + (size_t)row * 1024))[tid] = o;
}

// ------- transpose+cast 5 weight mats (1024x1024 f32, [k][n]) -> fp16 [n][k] -------
__global__ __launch_bounds__(256) void transpose5(
    const float* __restrict__ Wq, const float* __restrict__ Wk,
    const float* __restrict__ Wv, const float* __restrict__ Wa,
    const float* __restrict__ Wo, f16* __restrict__ wcat, f16* __restrict__ wot)
{
    __shared__ float tile[32][33];
    const int z = blockIdx.z;
    const float* src = (z==0)?Wq:(z==1)?Wk:(z==2)?Wv:(z==3)?Wa:Wo;
    f16* dst = (z < 4) ? (wcat + (size_t)z * 1024 * 1024) : wot;
    const int bx = blockIdx.x * 32, by = blockIdx.y * 32;
    const int tx = threadIdx.x, ty = threadIdx.y;
    #pragma unroll
    for (int i = 0; i < 4; ++i)
        tile[ty + i*8][tx] = src[(size_t)(by + ty + i*8) * 1024 + bx + tx];
    __syncthreads();
    #pragma unroll
    for (int i = 0; i < 4; ++i)
        dst[(size_t)(bx + ty + i*8) * 1024 + by + tx] = (f16)tile[tx][ty + i*8];
}

// ---------------- fp16 MFMA GEMM, B transposed (N x K). BM=BN=128, BK=64 ----------------
template<int MODE>
__global__ __launch_bounds__(256) void gemm_bt(
    const f16* __restrict__ A, const f16* __restrict__ Bt,
    int M, int N, int K,
    const float* __restrict__ ba, const float* __restrict__ resid,
    float* __restrict__ Cf,
    f16* __restrict__ Qb, f16* __restrict__ Kb,
    f16* __restrict__ Vb, f16* __restrict__ Ab)
{
    __shared__ f16 As[128 * 72];
    __shared__ f16 Bs[128 * 72];
    const int tid = threadIdx.x;
    const int bm = blockIdx.x, bn = blockIdx.y;
    const int wv = tid >> 6, lane = tid & 63;
    const int l15 = lane & 15, quad = lane >> 4;
    const int mb = (wv >> 1) * 64, nb = (wv & 1) * 64;
    v4f acc[4][4];
    const v4f vzero = {0.0f, 0.0f, 0.0f, 0.0f};
    #pragma unroll
    for (int i = 0; i < 4; ++i)
        #pragma unroll
        for (int j = 0; j < 4; ++j) acc[i][j] = vzero;

    const f16* Ag = A  + (size_t)bm * 128 * K;
    const f16* Bg = Bt + (size_t)bn * 128 * K;

    for (int k0 = 0; k0 < K; k0 += 64){
        __syncthreads();
        #pragma unroll
        for (int it = 0; it < 4; ++it){
            const int ch = tid + it * 256;
            const int r = ch >> 3, c = ch & 7;
            const uint4 da = *(const uint4*)(Ag + (size_t)r * K + k0 + c * 8);
            *(uint4*)(&As[r * 72 + c * 8]) = da;
            const uint4 db = *(const uint4*)(Bg + (size_t)r * K + k0 + c * 8);
            *(uint4*)(&Bs[r * 72 + c * 8]) = db;
        }
        __syncthreads();
        #pragma unroll
        for (int kk = 0; kk < 2; ++kk){
            v8h af[4], bfr[4];
            #pragma unroll
            for (int i = 0; i < 4; ++i){
                af[i]  = *(const v8h*)(&As[(mb + i*16 + l15) * 72 + kk*32 + quad*8]);
                bfr[i] = *(const v8h*)(&Bs[(nb + i*16 + l15) * 72 + kk*32 + quad*8]);
            }
            #pragma unroll
            for (int i = 0; i < 4; ++i)
                #pragma unroll
                for (int j = 0; j < 4; ++j)
                    acc[i][j] = __builtin_amdgcn_mfma_f32_16x16x32_f16(af[i], bfr[j], acc[i][j], 0, 0, 0);
        }
    }
    const int seg = (bn * 128) >> 10;
    f16* dst = (seg == 0) ? Qb : (seg == 1) ? Kb : (seg == 2) ? Vb : Ab;
    #pragma unroll
    for (int i = 0; i < 4; ++i){
        #pragma unroll
        for (int j = 0; j < 4; ++j){
            const int col = bn * 128 + nb + j * 16 + l15;
            const int c   = col & 1023;
            #pragma unroll
            for (int r = 0; r < 4; ++r){
                const int row = bm * 128 + mb + i * 16 + quad * 4 + r;
                float val = acc[i][j][r];
                if (MODE == 0){
                    if (seg == 3) val = sigmoidf_(val + ba[c]);
                    dst[(size_t)row * 1024 + c] = (f16)val;
                } else {
                    Cf[(size_t)row * N + col] = val + resid[(size_t)row * N + col];
                }
            }
        }
    }
}

// ---------------- beta: sigmoid(xn @ Wb + bb), stored chain-major [b*16+h][t] ----------------
__global__ __launch_bounds__(256) void beta_kernel(
    const f16* __restrict__ xn, const float* __restrict__ Wb,
    const float* __restrict__ bb, float* __restrict__ betaw)
{
    const int row = blockIdx.x;
    const int b = row >> 11, t = row & 2047;
    const int wv = threadIdx.x >> 6, lane = threadIdx.x & 63;
    const f16* xr = xn + (size_t)row * 1024;
    #pragma unroll
    for (int hh = 0; hh < 4; ++hh){
        const int h = wv * 4 + hh;
        float acc = 0.0f;
        #pragma unroll 4
        for (int k = lane; k < 1024; k += 64)
            acc += (float)xr[k] * Wb[k * 16 + h];
        acc = allreduce64(acc);
        if (lane == 0)
            betaw[((size_t)(b * 16 + h)) * 2048 + t] = sigmoidf_(acc + bb[h]);
    }
}

// ---------------- scan v7: WY tile algebra on MFMA with exact f16 hi/lo splits ----------------
// Same math as v6 (harness-verified): gauge Z, WY over 16-step tiles.
// All tile matmuls -> mfma_f32_16x16x32_f16 with hi/lo split packed on K:
//   A=(Xh|Xl) straight vs B dup  or  A dup vs B=(Yh;Yl)  computes X*Y EXACTLY
//   (f16 products exact, f32 accumulation) -> f32-class precision.
// Triangular solve (wave0, f32) overlaps next-tile global staging (waves 1-7).
#define SC 16
__global__ __launch_bounds__(512, 2) void scan_kernel(
    const f16* __restrict__ Qb, const f16* __restrict__ Kb,
    const f16* __restrict__ Vb, const f16* __restrict__ Ab,
    const float* __restrict__ beta, const float* __restrict__ rgm,
    f16* __restrict__ O)
{
    const int chain = blockIdx.x;           // b*16 + h
    const int b = chain >> 4, h = chain & 15;
    const int tid = threadIdx.x;
    const int wid = __builtin_amdgcn_readfirstlane(tid) >> 6;  // wave id 0..7
    const int l = tid & 63;
    const int jbase = wid << 3;                                // 8 M-rows per thread
    const float gm = sigmoidf_(rgm[h]);
    const int l15 = l & 15, q4 = l >> 4;

    // raw tiles + preamble state
    __shared__ f16 tQ[1024], tK[1024], tV[1024], tA[1024];
    __shared__ float betaT[SC], rnkT[SC];
    __shared__ float ktlT[1024];              // k_tilde f32
    __shared__ float Gc[1024];                // cumprod gates [t][d]
    __shared__ float mkP[8192];               // M-recurrence partials [t][w][l]
    // f16 split tables (halfword pitches chosen 16B-aligned per row)
    __shared__ f16 PhT[16*72], PlT[16*72], QhT[16*72], QlT[16*72];  // [t][d] A-ops
    __shared__ f16 Wcat[16*136], Ucat[16*136];   // [t][chunk-interleaved Wh|Wl] B-ops (pairs)
    __shared__ f16 WTcat[64*40], UTcat[64*40];   // [d][Wh(16)|Wl(16)] B-ops (commit); UT negated
    __shared__ f16 HTcat[64*40];                 // [e][Hh|Hl]
    __shared__ f16 VT[64*24];                    // [e][i] (V exact in f16)
    __shared__ f16 ZTcat[64*136];                // [e][chunk: Zh(16)|Zl(16)] B-op (P*Z)
    __shared__ f16 Cmcat[3*16*40];               // masked coeffs [m][t][Ch|Cl]; m:0=SL(PW),1=L(QW),2=-L(QU)
    __shared__ float ZsT[64*68];                 // f32 master of Z^T [e][d]
    __shared__ float Hs[16*68], Ob[16*68];       // f32 RHS / O accum [t][e]
    __shared__ float C2s[16*17];                 // f32 P*U^T (solve coeffs)

    float m[8];
    #pragma unroll
    for (int dd = 0; dd < 8; ++dd)
        m[dd] = (jbase + dd == l) ? 1e-6f : 0.0f;   // M0 = EPS*I

    const size_t cbase = ((size_t)(b * TT)) * 1024 + h * 64;
    const int tens = tid >> 7, rem = tid & 127;
    const int str = rem >> 3, j4 = rem & 7;
    const f16* sg = (tens == 0) ? Qb : (tens == 1) ? Kb : (tens == 2) ? Vb : Ab;
    f16* sl = (tens == 0) ? tQ : (tens == 1) ? tK : (tens == 2) ? tV : tA;

    // prologue: stage tile 0 + zero state
    {
        const uint4 d0 = *(const uint4*)(sg + cbase + (size_t)str * 1024 + j4 * 8);
        *(uint4*)(sl + str * 64 + j4 * 8) = d0;
        if (tid < SC) betaT[tid] = beta[(size_t)chain * TT + tid];
        for (int i = tid; i < 64*68; i += 512) ZsT[i] = 0.0f;
        for (int i = tid; i < 64*136; i += 512) ZTcat[i] = (f16)0.0f;
    }

    #pragma unroll 1
    for (int t0 = 0; t0 < TT; t0 += SC){
        __syncthreads();   // B0: raw tile + ZT ready

        // ---- P1: k-norms (2/wave) + G cumprod (wave 7) ----
        #pragma unroll
        for (int rr = 0; rr < 2; ++rr){
            const int t = (wid << 1) + rr;
            const float kv = (float)tK[t * 64 + l];
            const float nk = wave_sum64(kv * kv);
            if (l == 0) rnkT[t] = __builtin_amdgcn_rcpf(fmaxf(sqrtf(nk), 1e-12f));
        }
        if (wid == 7){
            float g = 1.0f;
            #pragma unroll
            for (int t = 0; t < SC; ++t){
                g *= (float)tA[t * 64 + l];
                Gc[t * 64 + l] = g;
            }
        }
        __syncthreads();   // B1

        // ---- P2: bulk M recurrence + mk partials (verbatim v6) ----
        #pragma unroll
        for (int t = 0; t < SC; ++t){
            const float knl = (float)tK[t * 64 + l] * rnkT[t];
            float knj2[8];
            #pragma unroll
            for (int dd = 0; dd < 8; ++dd) knj2[dd] = rlane(knl, jbase + dd);
            float mk0 = 0.f, mk1 = 0.f;
            #pragma unroll
            for (int dd = 0; dd < 8; dd += 2){
                m[dd]     = fmaf(gm, m[dd],     knl * knj2[dd]);
                mk0 = fmaf(m[dd], knj2[dd], mk0);
                m[dd + 1] = fmaf(gm, m[dd + 1], knl * knj2[dd + 1]);
                mk1 = fmaf(m[dd + 1], knj2[dd + 1], mk1);
            }
            mkP[(t << 9) + (wid << 6) + l] = mk0 + mk1;
        }
        __syncthreads();   // B2

        // ---- P3: reduce mk + normalize ktl (2/wave) + VT build ----
        #pragma unroll
        for (int rr = 0; rr < 2; ++rr){
            const int t = (wid << 1) + rr;
            float mkf = 0.f;
            #pragma unroll
            for (int w2 = 0; w2 < 8; ++w2) mkf += mkP[(t << 9) + (w2 << 6) + l];
            const float nmk = wave_sum64(mkf * mkf);
            ktlT[t * 64 + l] = mkf * __builtin_amdgcn_rcpf(fmaxf(sqrtf(nmk), 1e-6f));
        }
        #pragma unroll
        for (int half = 0; half < 2; ++half){
            const int idx = tid + half * 512;
            const int e = idx & 63, i = idx >> 6;
            VT[e * 24 + i] = tV[i * 64 + e];
        }
        __syncthreads();   // B3

        // ---- P4: gauge tables, f16 hi/lo splits ----
        #pragma unroll
        for (int half = 0; half < 2; ++half){
            const int idx = tid + half * 512;
            const int t = idx >> 6, d = idx & 63;
            const float g    = Gc[t * 64 + d];
            const float invg = 1.0f / g;
            const float kn   = (float)tK[t * 64 + d] * rnkT[t];
            const float bt   = betaT[t];
            const float pv = kn * g;
            const float uv = bt * ktlT[t * 64 + d] * invg;
            const float wv = bt * kn * invg;
            const float qv = (float)tQ[t * 64 + d] * g;
            const f16 ph = (f16)pv, qh = (f16)qv, wh = (f16)wv, uh = (f16)uv;
            const f16 pl = (f16)(pv - (float)ph), ql = (f16)(qv - (float)qh);
            const f16 wl = (f16)(wv - (float)wh), ul = (f16)(uv - (float)uh);
            PhT[t * 72 + d] = ph;  PlT[t * 72 + d] = pl;
            QhT[t * 72 + d] = qh;  QlT[t * 72 + d] = ql;
            const int cc = ((d >> 4) << 5) + (d & 15);
            Wcat[t * 136 + cc] = wh;  Wcat[t * 136 + cc + 16] = wl;
            Ucat[t * 136 + cc] = uh;  Ucat[t * 136 + cc + 16] = ul;
            WTcat[d * 40 + t] = wh;   WTcat[d * 40 + 16 + t] = wl;
            const float nuv = -uv;
            const f16 nuh = (f16)nuv;
            UTcat[d * 40 + t] = nuh;  UTcat[d * 40 + 16 + t] = (f16)(nuv - (float)nuh);
        }
        __syncthreads();   // B4

        // ---- Phase A: [P;Q']*Z0 (all waves) + pair matrices (waves 0-3) ----
        {
            const int et = wid & 3;
            const f16* Amh = (wid < 4) ? PhT : QhT;
            const f16* Aml = (wid < 4) ? PlT : QlT;
            const int ar = l15 * 72 + (q4 & 1) * 8;       // A dup-read (quad-masked)
            const int br = (et * 16 + l15) * 136 + q4 * 8; // B straight chunk read
            v4f acc = {0.f, 0.f, 0.f, 0.f};
            #pragma unroll
            for (int c = 0; c < 4; ++c){
                const v8h ah = *(const v8h*)(Amh + ar + c * 16);
                const v8h al = *(const v8h*)(Aml + ar + c * 16);
                const v8h bz = *(const v8h*)(ZTcat + br + c * 32);
                acc = __builtin_amdgcn_mfma_f32_16x16x32_f16(ah, bz, acc, 0, 0, 0);
                acc = __builtin_amdgcn_mfma_f32_16x16x32_f16(al, bz, acc, 0, 0, 0);
            }
            float* Rdst = (wid < 4) ? Hs : Ob;
            #pragma unroll
            for (int j = 0; j < 4; ++j)
                Rdst[(q4 * 4 + j) * 68 + et * 16 + l15] = acc[j];

            if (wid < 4){
                // wave0: P*W^T -> C1(SL)   wave1: P*U^T -> C2s (solve)
                // wave2: Q*W^T -> C3(L)    wave3: Q*U^T -> C4(L, negated)
                const f16* A2h = (wid < 2) ? PhT : QhT;
                const f16* A2l = (wid < 2) ? PlT : QlT;
                const f16* Bp  = (wid & 1) ? Ucat : Wcat;
                const int br2 = l15 * 136 + q4 * 8;
                v4f pacc = {0.f, 0.f, 0.f, 0.f};
                #pragma unroll
                for (int c = 0; c < 4; ++c){
                    const v8h a2h = *(const v8h*)(A2h + ar + c * 16);
                    const v8h a2l = *(const v8h*)(A2l + ar + c * 16);
                    const v8h bw  = *(const v8h*)(Bp + br2 + c * 32);
                    pacc = __builtin_amdgcn_mfma_f32_16x16x32_f16(a2h, bw, pacc, 0, 0, 0);
                    pacc = __builtin_amdgcn_mfma_f32_16x16x32_f16(a2l, bw, pacc, 0, 0, 0);
                }
                if (wid == 1){
                    #pragma unroll
                    for (int j = 0; j < 4; ++j)
                        C2s[(q4 * 4 + j) * 17 + l15] = pacc[j];
                } else {
                    const int mm = (wid == 0) ? 0 : (wid == 2) ? 1 : 2;
                    #pragma unroll
                    for (int j = 0; j < 4; ++j){
                        const int t = q4 * 4 + j, i = l15;
                        float v = ((mm == 0) ? (i < t) : (i <= t)) ? pacc[j] : 0.0f;
                        if (mm == 2) v = -v;
                        const f16 vh = (f16)v;
                        Cmcat[mm * 640 + t * 40 + i] = vh;
                        Cmcat[mm * 640 + t * 40 + 16 + i] = (f16)(v - (float)vh);
                    }
                }
            }
        }
        __syncthreads();   // B5

        // ---- Phase C: Hs += SL(C1)*V (w0-3) ; Ob += L(C3)*V (w4-7) ----
        {
            const int et = wid & 3;
            const int mm = (wid < 4) ? 0 : 1;
            float* Rd = (wid < 4) ? Hs : Ob;
            const v8h ac = *(const v8h*)(Cmcat + mm * 640 + l15 * 40 + q4 * 8);
            const v8h bv = *(const v8h*)(VT + (et * 16 + l15) * 24 + (q4 & 1) * 8);
            v4f acc;
            #pragma unroll
            for (int j = 0; j < 4; ++j) acc[j] = Rd[(q4 * 4 + j) * 68 + et * 16 + l15];
            acc = __builtin_amdgcn_mfma_f32_16x16x32_f16(ac, bv, acc, 0, 0, 0);
            #pragma unroll
            for (int j = 0; j < 4; ++j) Rd[(q4 * 4 + j) * 68 + et * 16 + l15] = acc[j];
        }
        __syncthreads();   // B6

        // ---- Phase D: solve (wave 0) || stage next tile (waves 1-7) ----
        if (wid == 0){
            float hreg[SC];
            #pragma unroll
            for (int t = 0; t < SC; ++t){
                float x = Hs[t * 68 + l];
                #pragma unroll
                for (int i = 0; i < SC; ++i)
                    if (i < t) x = fmaf(-C2s[t * 17 + i], hreg[i], x);
                hreg[t] = x;
                const f16 hh = (f16)x;
                HTcat[l * 40 + t] = hh;
                HTcat[l * 40 + 16 + t] = (f16)(x - (float)hh);
            }
        } else if (t0 + SC < TT){
            const int base = tid - 64;
            #pragma unroll
            for (int rep = 0; rep < 2; ++rep){
                const int ch = base + rep * 448;
                if (ch < 512){
                    const int tens2 = ch >> 7, rem2 = ch & 127;
                    const int str2 = rem2 >> 3, jj = rem2 & 7;
                    const f16* sgp = (tens2 == 0) ? Qb : (tens2 == 1) ? Kb : (tens2 == 2) ? Vb : Ab;
                    f16* slp = (tens2 == 0) ? tQ : (tens2 == 1) ? tK : (tens2 == 2) ? tV : tA;
                    const uint4 dd0 = *(const uint4*)(sgp + cbase + (size_t)(t0 + SC + str2) * 1024 + jj * 8);
                    *(uint4*)(slp + str2 * 64 + jj * 8) = dd0;
                }
            }
            if (base < SC) betaT[base] = beta[(size_t)chain * TT + t0 + SC + base];
        }
        __syncthreads();   // B7

        // ---- Phase F: O finalize (w0-3) + Z^T commit (all waves, 2 tiles each) ----
        {
            const int et = wid & 3;
            const int arow = et * 16 + l15;
            const v8h aV  = *(const v8h*)(VT + arow * 24 + (q4 & 1) * 8);
            const v8h aHh = *(const v8h*)(HTcat + arow * 40 + (q4 & 1) * 8);
            const v8h aHl = *(const v8h*)(HTcat + arow * 40 + 16 + (q4 & 1) * 8);

            if (wid < 4){
                // O = Ob + (-C4)*H  (C4 pre-negated; H = Hh + Hl via two dup-B MFMAs)
                const v8h aC = *(const v8h*)(Cmcat + 2 * 640 + l15 * 40 + q4 * 8);
                v4f acc2;
                #pragma unroll
                for (int j = 0; j < 4; ++j) acc2[j] = Ob[(q4 * 4 + j) * 68 + et * 16 + l15];
                acc2 = __builtin_amdgcn_mfma_f32_16x16x32_f16(aC, aHh, acc2, 0, 0, 0);
                acc2 = __builtin_amdgcn_mfma_f32_16x16x32_f16(aC, aHl, acc2, 0, 0, 0);
                #pragma unroll
                for (int j = 0; j < 4; ++j){
                    const int t = q4 * 4 + j;
                    O[cbase + (size_t)(t0 + t) * 1024 + et * 16 + l15] = (f16)acc2[j];
                }
            }

            #pragma unroll
            for (int tt2 = 0; tt2 < 2; ++tt2){
                const int dt = (wid >> 2) * 2 + tt2;
                const v8h bW = *(const v8h*)(WTcat + (dt * 16 + l15) * 40 + q4 * 8);
                const v8h bU = *(const v8h*)(UTcat + (dt * 16 + l15) * 40 + q4 * 8);
                v4f acc;
                #pragma unroll
                for (int j = 0; j < 4; ++j)
                    acc[j] = ZsT[(et * 16 + q4 * 4 + j) * 68 + dt * 16 + l15];
                acc = __builtin_amdgcn_mfma_f32_16x16x32_f16(aV,  bW, acc, 0, 0, 0);
                acc = __builtin_amdgcn_mfma_f32_16x16x32_f16(aHh, bU, acc, 0, 0, 0);
                acc = __builtin_amdgcn_mfma_f32_16x16x32_f16(aHl, bU, acc, 0, 0, 0);
                const float gl = Gc[15 * 64 + dt * 16 + l15];
                #pragma unroll
                for (int j = 0; j < 4; ++j){
                    const float z = acc[j] * gl;
                    const int er = et * 16 + q4 * 4 + j;
                    ZsT[er * 68 + dt * 16 + l15] = z;
                    const f16 zh = (f16)z;
                    ZTcat[er * 136 + dt * 32 + l15] = zh;
                    ZTcat[er * 136 + dt * 32 + 16 + l15] = (f16)(z - (float)zh);
                }
            }
        }
        // loop-top barrier (B0) separates commit writes / staged raw from next tile
    }
}

// ---------------- workspace layout (bytes), total ~107 MB ----------------
#define OFF_XN    ((size_t)0)                     // 16384*1024 f16 = 32 MB  (later: O)
#define OFF_WCAT  ((size_t)33554432)              // 4*1024*1024 f16 = 8 MB
#define OFF_WOT   ((size_t)41943040)              // 1024*1024 f16  =  2 MB
#define OFF_BETA  ((size_t)44040192)              // 128*2048 f32   =  1 MB
#define OFF_V     ((size_t)45088768)              // 16384*1024 f16 = 32 MB
#define OFF_A     ((size_t)78643200)              // 16384*1024 f16 = 32 MB
#define WS_NEED   ((size_t)112197632)

extern "C" void kernel_launch(void* const* d_in, const int* in_sizes, int n_in,
                              void* d_out, int out_size, void* d_ws, size_t ws_size,
                              hipStream_t stream)
{
    const float* x   = (const float*)d_in[0];
    const float* lng = (const float*)d_in[1];
    const float* lnb = (const float*)d_in[2];
    const float* Wq  = (const float*)d_in[3];
    const float* Wk  = (const float*)d_in[4];
    const float* Wv  = (const float*)d_in[5];
    const float* Wa  = (const float*)d_in[6];
    const float* ba  = (const float*)d_in[7];
    const float* Wb  = (const float*)d_in[8];
    const float* bb  = (const float*)d_in[9];
    const float* rgm = (const float*)d_in[10];
    const float* Wo  = (const float*)d_in[11];
    float* out = (float*)d_out;

    if (ws_size < WS_NEED){
        sentinel_fill<<<(out_size + 255) / 256, 256, 0, stream>>>(out, out_size);
        return;
    }

    char* ws = (char*)d_ws;
    f16*   xn   = (f16*)(ws + OFF_XN);
    f16*   wcat = (f16*)(ws + OFF_WCAT);
    f16*   wot  = (f16*)(ws + OFF_WOT);
    float* betw = (float*)(ws + OFF_BETA);
    f16*   Vbuf = (f16*)(ws + OFF_V);
    f16*   Abuf = (f16*)(ws + OFF_A);
    f16*   Qbuf = (f16*)d_out;                    // 32 MB
    f16*   Kbuf = Qbuf + (size_t)16384 * 1024;    // 32 MB (d_out total = 64 MB)
    f16*   Obuf = xn;                             // reuse xn slot after it's dead

    ln_kernel<<<16384, 256, 0, stream>>>(x, lng, lnb, xn);
    transpose5<<<dim3(32, 32, 5), dim3(32, 8), 0, stream>>>(Wq, Wk, Wv, Wa, Wo, wcat, wot);
    gemm_bt<0><<<dim3(128, 32), 256, 0, stream>>>(xn, wcat, 16384, 4096, 1024,
                                                  ba, nullptr, nullptr, Qbuf, Kbuf, Vbuf, Abuf);
    beta_kernel<<<16384, 256, 0, stream>>>(xn, Wb, bb, betw);
    scan_kernel<<<128, 512, 0, stream>>>(Qbuf, Kbuf, Vbuf, Abuf, betw, rgm, Obuf);
    gemm_bt<1><<<dim3(128, 8), 256, 0, stream>>>(Obuf, wot, 16384, 1024, 1024,
                                                 nullptr, x, out, nullptr, nullptr, nullptr, nullptr);
}

// Round 4
// 1710.989 us; speedup vs baseline: 1.4945x; 1.0081x over previous
//
#include <hip/hip_runtime.h>

typedef unsigned short u16;
typedef unsigned int   u32;
typedef _Float16       f16;
typedef __attribute__((ext_vector_type(4))) _Float16 v4h;
typedef __attribute__((ext_vector_type(8))) _Float16 v8h;   // MFMA A/B frag (4 VGPRs)
typedef __attribute__((ext_vector_type(4))) float    v4f;   // MFMA C/D frag

#define TT 2048
#define BB 8

static __device__ __forceinline__ float sigmoidf_(float x){
    return 1.0f / (1.0f + __expf(-x));
}
static __device__ __forceinline__ float allreduce64(float v){
    #pragma unroll
    for (int off = 32; off > 0; off >>= 1) v += __shfl_xor(v, off, 64);
    return v;
}

// Wave64 sum via DPP (VALU-only). row_shr 1/2/4/8 + row_bcast 15/31; lane 63 total.
static __device__ __forceinline__ float wave_sum64(float x){
    int t;
    t = __builtin_amdgcn_update_dpp(0, __float_as_int(x), 0x111, 0xf, 0xf, true); x += __int_as_float(t);
    t = __builtin_amdgcn_update_dpp(0, __float_as_int(x), 0x112, 0xf, 0xf, true); x += __int_as_float(t);
    t = __builtin_amdgcn_update_dpp(0, __float_as_int(x), 0x114, 0xf, 0xf, true); x += __int_as_float(t);
    t = __builtin_amdgcn_update_dpp(0, __float_as_int(x), 0x118, 0xf, 0xf, true); x += __int_as_float(t);
    t = __builtin_amdgcn_update_dpp(0, __float_as_int(x), 0x142, 0xf, 0xf, true); x += __int_as_float(t);
    t = __builtin_amdgcn_update_dpp(0, __float_as_int(x), 0x143, 0xf, 0xf, true); x += __int_as_float(t);
    return __int_as_float(__builtin_amdgcn_readlane(__float_as_int(x), 63));
}

// ---------------- diagnostic: fills d_out with sentinel if ws too small ----------------
__global__ __launch_bounds__(256) void sentinel_fill(float* __restrict__ out, int n){
    int i = blockIdx.x * 256 + threadIdx.x;
    if (i < n) out[i] = 12345.0f;
}

// ---------------- LayerNorm: x (16384x1024 f32) -> xn (fp16) ----------------
__global__ __launch_bounds__(256) void ln_kernel(
    const float* __restrict__ x, const float* __restrict__ g,
    const float* __restrict__ bta, f16* __restrict__ xn)
{
    const int row = blockIdx.x;
    const int tid = threadIdx.x;
    const float4 v = ((const float4*)(x + (size_t)row * 1024))[tid];
    float s  = v.x + v.y + v.z + v.w;
    float s2 = v.x*v.x + v.y*v.y + v.z*v.z + v.w*v.w;
    #pragma unroll
    for (int off = 32; off > 0; off >>= 1){
        s  += __shfl_xor(s,  off, 64);
        s2 += __shfl_xor(s2, off, 64);
    }
    __shared__ float rs[4], rq[4];
    const int wv = tid >> 6, lane = tid & 63;
    if (lane == 0){ rs[wv] = s; rq[wv] = s2; }
    __syncthreads();
    s  = rs[0] + rs[1] + rs[2] + rs[3];
    s2 = rq[0] + rq[1] + rq[2] + rq[3];
    const float mu   = s * (1.0f / 1024.0f);
    const float var  = s2 * (1.0f / 1024.0f) - mu * mu;
    const float rstd = rsqrtf(var + 1e-5f);
    const float4 gv = ((const float4*)g)[tid];
    const float4 bv = ((const float4*)bta)[tid];
    v4h o;
    o.x = (f16)((v.x - mu) * rstd * gv.x + bv.x);
    o.y = (f16)((v.y - mu) * rstd * gv.y + bv.y);
    o.z = (f16)((v.z - mu) * rstd * gv.z + bv.z);
    o.w = (f16)((v.w - mu) * rstd * gv.w + bv.w);
    ((v4h*)(xn + (size_t)row * 1024))[tid] = o;
}

// ------- transpose+cast 5 weight mats (1024x1024 f32, [k][n]) -> fp16 [n][k] -------
__global__ __launch_bounds__(256) void transpose5(
    const float* __restrict__ Wq, const float* __restrict__ Wk,
    const float* __restrict__ Wv, const float* __restrict__ Wa,
    const float* __restrict__ Wo, f16* __restrict__ wcat, f16* __restrict__ wot)
{
    __shared__ float tile[32][33];
    const int z = blockIdx.z;
    const float* src = (z==0)?Wq:(z==1)?Wk:(z==2)?Wv:(z==3)?Wa:Wo;
    f16* dst = (z < 4) ? (wcat + (size_t)z * 1024 * 1024) : wot;
    const int bx = blockIdx.x * 32, by = blockIdx.y * 32;
    const int tx = threadIdx.x, ty = threadIdx.y;
    #pragma unroll
    for (int i = 0; i < 4; ++i)
        tile[ty + i*8][tx] = src[(size_t)(by + ty + i*8) * 1024 + bx + tx];
    __syncthreads();
    #pragma unroll
    for (int i = 0; i < 4; ++i)
        dst[(size_t)(bx + ty + i*8) * 1024 + by + tx] = (f16)tile[tx][ty + i*8];
}

// ---------------- fp16 MFMA GEMM, B transposed (N x K). BM=BN=128, BK=64 ----------------
template<int MODE>
__global__ __launch_bounds__(256) void gemm_bt(
    const f16* __restrict__ A, const f16* __restrict__ Bt,
    int M, int N, int K,
    const float* __restrict__ ba, const float* __restrict__ resid,
    float* __restrict__ Cf,
    f16* __restrict__ Qb, f16* __restrict__ Kb,
    f16* __restrict__ Vb, f16* __restrict__ Ab)
{
    __shared__ f16 As[128 * 72];
    __shared__ f16 Bs[128 * 72];
    const int tid = threadIdx.x;
    const int bm = blockIdx.x, bn = blockIdx.y;
    const int wv = tid >> 6, lane = tid & 63;
    const int l15 = lane & 15, quad = lane >> 4;
    const int mb = (wv >> 1) * 64, nb = (wv & 1) * 64;
    v4f acc[4][4];
    const v4f vzero = {0.0f, 0.0f, 0.0f, 0.0f};
    #pragma unroll
    for (int i = 0; i < 4; ++i)
        #pragma unroll
        for (int j = 0; j < 4; ++j) acc[i][j] = vzero;

    const f16* Ag = A  + (size_t)bm * 128 * K;
    const f16* Bg = Bt + (size_t)bn * 128 * K;

    for (int k0 = 0; k0 < K; k0 += 64){
        __syncthreads();
        #pragma unroll
        for (int it = 0; it < 4; ++it){
            const int ch = tid + it * 256;
            const int r = ch >> 3, c = ch & 7;
            const uint4 da = *(const uint4*)(Ag + (size_t)r * K + k0 + c * 8);
            *(uint4*)(&As[r * 72 + c * 8]) = da;
            const uint4 db = *(const uint4*)(Bg + (size_t)r * K + k0 + c * 8);
            *(uint4*)(&Bs[r * 72 + c * 8]) = db;
        }
        __syncthreads();
        #pragma unroll
        for (int kk = 0; kk < 2; ++kk){
            v8h af[4], bfr[4];
            #pragma unroll
            for (int i = 0; i < 4; ++i){
                af[i]  = *(const v8h*)(&As[(mb + i*16 + l15) * 72 + kk*32 + quad*8]);
                bfr[i] = *(const v8h*)(&Bs[(nb + i*16 + l15) * 72 + kk*32 + quad*8]);
            }
            #pragma unroll
            for (int i = 0; i < 4; ++i)
                #pragma unroll
                for (int j = 0; j < 4; ++j)
                    acc[i][j] = __builtin_amdgcn_mfma_f32_16x16x32_f16(af[i], bfr[j], acc[i][j], 0, 0, 0);
        }
    }
    const int seg = (bn * 128) >> 10;
    f16* dst = (seg == 0) ? Qb : (seg == 1) ? Kb : (seg == 2) ? Vb : Ab;
    #pragma unroll
    for (int i = 0; i < 4; ++i){
        #pragma unroll
        for (int j = 0; j < 4; ++j){
            const int col = bn * 128 + nb + j * 16 + l15;
            const int c   = col & 1023;
            #pragma unroll
            for (int r = 0; r < 4; ++r){
                const int row = bm * 128 + mb + i * 16 + quad * 4 + r;
                float val = acc[i][j][r];
                if (MODE == 0){
                    if (seg == 3) val = sigmoidf_(val + ba[c]);
                    dst[(size_t)row * 1024 + c] = (f16)val;
                } else {
                    Cf[(size_t)row * N + col] = val + resid[(size_t)row * N + col];
                }
            }
        }
    }
}

// ---------------- beta: sigmoid(xn @ Wb + bb), stored chain-major [b*16+h][t] ----------------
__global__ __launch_bounds__(256) void beta_kernel(
    const f16* __restrict__ xn, const float* __restrict__ Wb,
    const float* __restrict__ bb, float* __restrict__ betaw)
{
    const int row = blockIdx.x;
    const int b = row >> 11, t = row & 2047;
    const int wv = threadIdx.x >> 6, lane = threadIdx.x & 63;
    const f16* xr = xn + (size_t)row * 1024;
    #pragma unroll
    for (int hh = 0; hh < 4; ++hh){
        const int h = wv * 4 + hh;
        float acc = 0.0f;
        #pragma unroll 4
        for (int k = lane; k < 1024; k += 64)
            acc += (float)xr[k] * Wb[k * 16 + h];
        acc = allreduce64(acc);
        if (lane == 0)
            betaw[((size_t)(b * 16 + h)) * 2048 + t] = sigmoidf_(acc + bb[h]);
    }
}

// ---------------- scan v8: Gram-matrix M-recurrence on MFMA ----------------
// v7's WY/MFMA S-side kept verbatim. New M-side (replaces P2/P3 VALU recurrence):
//   Mk_t = gm^{t+1} (M0 kn_t) + sum_{i<=t} gm^{t-i} (kn_i . kn_t) kn_i
//   -> Gram G = Kn Kn^T (8 MFMA), D = tril(gm-powers * G), DK = D Kn (8 MFMA),
//      N = M0 Kn^T (32 MFMA), M0 commit = gm^16 M0 + Kn^T E Kn (32 MFMA, in
//      solve/staging shadow). Exact f16 hi/lo splits throughout (v7-verified).
// State M0 and Z live as f16 split pairs (decay/requant error ~1e-5, in tolerance).
#define SC 16
__global__ __launch_bounds__(512, 2) void scan_kernel(
    const f16* __restrict__ Qb, const f16* __restrict__ Kb,
    const f16* __restrict__ Vb, const f16* __restrict__ Ab,
    const float* __restrict__ beta, const float* __restrict__ rgm,
    f16* __restrict__ O)
{
    const int chain = blockIdx.x;           // b*16 + h
    const int b = chain >> 4, h = chain & 15;
    const int tid = threadIdx.x;
    const int wid = __builtin_amdgcn_readfirstlane(tid) >> 6;  // wave id 0..7
    const int l = tid & 63;
    const float gm = sigmoidf_(rgm[h]);
    const int l15 = l & 15, q4 = l >> 4;

    // raw tiles + scalars
    __shared__ f16 tQ[1024], tK[1024], tV[1024], tA[1024];
    __shared__ float betaT[SC], rnkT[SC], gmps[20];
    __shared__ float GcT[64*18], IGcT[64*18], ktlTT[64*18];   // [d][t] transposed
    // Kn split tables
    __shared__ f16 KnAh[16*72], KnAl[16*72];     // [t][d] A-operand
    __shared__ f16 KnBcat[16*136];               // [t][chunk h|l] B-operand (K=64)
    __shared__ f16 KnTcat[64*40], KnTEcat[64*40];// [d][th|tl] dual-use A/B (K=16)
    __shared__ f16 Dcat[16*40];                  // tril gm-weighted Gram
    __shared__ f16 M0h[64*72], M0l[64*72];       // M0 state (split pair)
    // gauge tables (v7)
    __shared__ f16 PhT[16*72], PlT[16*72], QhT[16*72], QlT[16*72];
    __shared__ f16 Wcat[16*136], Ucat[16*136];
    __shared__ f16 WTcat[64*40], UTcat[64*40];   // UT negated
    __shared__ f16 HTcat[64*40];
    __shared__ f16 VT[64*24];
    __shared__ f16 ZTcat[64*136];                // Z^T state (split pair)
    __shared__ f16 Cmcat[3*16*40];               // 0=SL(PW),1=L(QW),2=-L(QU)
    __shared__ float Hs[16*68], Ob[16*68];       // f32 RHS / O accum; aliased: Nf=Hs[64][17], MkF=Ob[16][68]
    __shared__ float C2s[16*17];                 // f32 P*U^T (solve coeffs)

    const size_t cbase = ((size_t)(b * TT)) * 1024 + h * 64;
    const int tens = tid >> 7, rem = tid & 127;
    const int str = rem >> 3, j4 = rem & 7;
    const f16* sg = (tens == 0) ? Qb : (tens == 1) ? Kb : (tens == 2) ? Vb : Ab;
    f16* sl = (tens == 0) ? tQ : (tens == 1) ? tK : (tens == 2) ? tV : tA;

    // prologue: stage tile 0, zero Z and M0, gm powers
    {
        const uint4 d0 = *(const uint4*)(sg + cbase + (size_t)str * 1024 + j4 * 8);
        *(uint4*)(sl + str * 64 + j4 * 8) = d0;
        if (tid < SC) betaT[tid] = beta[(size_t)chain * TT + tid];
        for (int i = tid; i < 64*136; i += 512) ZTcat[i] = (f16)0.0f;
        for (int i = tid; i < 64*72; i += 512){ M0h[i] = (f16)0.0f; M0l[i] = (f16)0.0f; }
        if (tid == 0){
            float g = 1.0f;
            #pragma unroll
            for (int k = 0; k <= 16; ++k){ gmps[k] = g; g *= gm; }
        }
    }
    __syncthreads();
    if (tid < 64) M0h[tid * 73] = (f16)1e-6f;     // M0 = EPS*I

    #pragma unroll 1
    for (int t0 = 0; t0 < TT; t0 += SC){
        __syncthreads();   // B0: raw tile + ZT + M0 ready

        // ---- PH1: k-norms (2/wave) + G cumprod & rcp (wave 7) ----
        #pragma unroll
        for (int rr = 0; rr < 2; ++rr){
            const int t = (wid << 1) + rr;
            const float kv = (float)tK[t * 64 + l];
            const float nk = wave_sum64(kv * kv);
            if (l == 0) rnkT[t] = __builtin_amdgcn_rcpf(fmaxf(sqrtf(nk), 1e-12f));
        }
        if (wid == 7){
            float g = 1.0f;
            #pragma unroll
            for (int t = 0; t < SC; ++t){
                g *= (float)tA[t * 64 + l];
                GcT[l * 18 + t]  = g;
                IGcT[l * 18 + t] = __builtin_amdgcn_rcpf(g);
            }
        }
        __syncthreads();   // B1

        // ---- PH2: Kn split tables (both layouts) + VT ----
        #pragma unroll
        for (int half = 0; half < 2; ++half){
            const int idx = tid + half * 512;
            {   // row-major: KnA h/l + KnBcat
                const int t = idx >> 6, d = idx & 63;
                const float kn = (float)tK[t * 64 + d] * rnkT[t];
                const f16 kh = (f16)kn; const f16 kl = (f16)(kn - (float)kh);
                KnAh[t * 72 + d] = kh;  KnAl[t * 72 + d] = kl;
                const int cc = ((d >> 4) << 5) + (d & 15);
                KnBcat[t * 136 + cc] = kh;  KnBcat[t * 136 + cc + 16] = kl;
            }
            {   // transposed: KnTcat + E-scaled KnTEcat
                const int d2 = idx >> 4, t2 = idx & 15;
                const float kn2 = (float)tK[t2 * 64 + d2] * rnkT[t2];
                const f16 kh2 = (f16)kn2;
                KnTcat[d2 * 40 + t2]      = kh2;
                KnTcat[d2 * 40 + 16 + t2] = (f16)(kn2 - (float)kh2);
                const float ke = kn2 * gmps[15 - t2];
                const f16 keh = (f16)ke;
                KnTEcat[d2 * 40 + t2]      = keh;
                KnTEcat[d2 * 40 + 16 + t2] = (f16)(ke - (float)keh);
            }
            {   // VT
                const int e = idx & 63, i2 = idx >> 6;
                VT[e * 24 + i2] = tV[i2 * 64 + e];
            }
        }
        __syncthreads();   // B2

        // ---- PH3: Gram+D (wave 0), N = M0 Kn^T (waves 1-4) ----
        if (wid == 0){
            const int ar = l15 * 72 + (q4 & 1) * 8;
            const int br = l15 * 136 + q4 * 8;
            v4f g4 = {0.f, 0.f, 0.f, 0.f};
            #pragma unroll
            for (int c = 0; c < 4; ++c)
                g4 = __builtin_amdgcn_mfma_f32_16x16x32_f16(
                        *(const v8h*)(KnAh + ar + c * 16),
                        *(const v8h*)(KnBcat + br + c * 32), g4, 0, 0, 0);
            #pragma unroll
            for (int c = 0; c < 4; ++c)
                g4 = __builtin_amdgcn_mfma_f32_16x16x32_f16(
                        *(const v8h*)(KnAl + ar + c * 16),
                        *(const v8h*)(KnBcat + br + c * 32), g4, 0, 0, 0);
            #pragma unroll
            for (int j = 0; j < 4; ++j){
                const int t = q4 * 4 + j, i = l15;
                const float dv = (i <= t) ? g4[j] * gmps[t - i] : 0.0f;
                const f16 dh = (f16)dv;
                Dcat[t * 40 + i]      = dh;
                Dcat[t * 40 + 16 + i] = (f16)(dv - (float)dh);
            }
        } else if (wid <= 4){
            const int rt = wid - 1;
            const int ar = (rt * 16 + l15) * 72 + (q4 & 1) * 8;
            const int br = l15 * 136 + q4 * 8;
            v4f acc = {0.f, 0.f, 0.f, 0.f};
            #pragma unroll
            for (int c = 0; c < 4; ++c)
                acc = __builtin_amdgcn_mfma_f32_16x16x32_f16(
                        *(const v8h*)(M0h + ar + c * 16),
                        *(const v8h*)(KnBcat + br + c * 32), acc, 0, 0, 0);
            #pragma unroll
            for (int c = 0; c < 4; ++c)
                acc = __builtin_amdgcn_mfma_f32_16x16x32_f16(
                        *(const v8h*)(M0l + ar + c * 16),
                        *(const v8h*)(KnBcat + br + c * 32), acc, 0, 0, 0);
            #pragma unroll
            for (int j = 0; j < 4; ++j)
                Hs[(rt * 16 + q4 * 4 + j) * 17 + l15] = acc[j];   // Nf alias
        }
        __syncthreads();   // B3

        // ---- PH4: DK + Mk combine (waves 0-3) || P/Q/W tables (waves 4-7) ----
        if (wid < 4){
            const int et = wid;
            const int arD = l15 * 40 + (q4 & 1) * 8;
            const int brD = (et * 16 + l15) * 40 + q4 * 8;
            v4f acc = {0.f, 0.f, 0.f, 0.f};
            acc = __builtin_amdgcn_mfma_f32_16x16x32_f16(
                    *(const v8h*)(Dcat + arD), *(const v8h*)(KnTcat + brD), acc, 0, 0, 0);
            acc = __builtin_amdgcn_mfma_f32_16x16x32_f16(
                    *(const v8h*)(Dcat + arD + 16), *(const v8h*)(KnTcat + brD), acc, 0, 0, 0);
            #pragma unroll
            for (int j = 0; j < 4; ++j){
                const int t = q4 * 4 + j, d = et * 16 + l15;
                Ob[t * 68 + d] = acc[j] + gmps[t + 1] * Hs[d * 17 + t];   // MkF alias
            }
        } else {
            #pragma unroll
            for (int k = 0; k < 4; ++k){
                const int idx = (tid - 256) + k * 256;
                const int t = idx >> 6, d = idx & 63;
                const float g  = GcT[d * 18 + t];
                const float ig = IGcT[d * 18 + t];
                const float kn = (float)tK[t * 64 + d] * rnkT[t];
                const float bt = betaT[t];
                const float pv = kn * g;
                const float qv = (float)tQ[t * 64 + d] * g;
                const float wv = bt * kn * ig;
                const f16 ph = (f16)pv, qh = (f16)qv, wh = (f16)wv;
                PhT[t * 72 + d] = ph;  PlT[t * 72 + d] = (f16)(pv - (float)ph);
                QhT[t * 72 + d] = qh;  QlT[t * 72 + d] = (f16)(qv - (float)qh);
                const int cc = ((d >> 4) << 5) + (d & 15);
                Wcat[t * 136 + cc] = wh;  Wcat[t * 136 + cc + 16] = (f16)(wv - (float)wh);
            }
        }
        __syncthreads();   // B4

        // ---- PH5: ktl normalize (2/wave) ----
        #pragma unroll
        for (int rr = 0; rr < 2; ++rr){
            const int t = (wid << 1) + rr;
            const float x = Ob[t * 68 + l];                  // MkF
            const float nm = wave_sum64(x * x);
            ktlTT[l * 18 + t] = x * __builtin_amdgcn_rcpf(fmaxf(sqrtf(nm), 1e-6f));
        }
        __syncthreads();   // B5

        // ---- PH6: U tables (row-major w0-3, transposed+W^T w4-7) ----
        if (wid < 4){
            #pragma unroll
            for (int k = 0; k < 4; ++k){
                const int idx = tid + k * 256;
                const int t = idx >> 6, d = idx & 63;
                const float uv = betaT[t] * ktlTT[d * 18 + t] * IGcT[d * 18 + t];
                const f16 uh = (f16)uv;
                const int cc = ((d >> 4) << 5) + (d & 15);
                Ucat[t * 136 + cc] = uh;  Ucat[t * 136 + cc + 16] = (f16)(uv - (float)uh);
            }
        } else {
            #pragma unroll
            for (int k = 0; k < 4; ++k){
                const int idx = (tid - 256) + k * 256;
                const int d = idx >> 4, t = idx & 15;
                const float ig = IGcT[d * 18 + t];
                const float bt = betaT[t];
                const float kn = (float)KnTcat[d * 40 + t] + (float)KnTcat[d * 40 + 16 + t];
                const float wv = bt * kn * ig;
                const f16 wh = (f16)wv;
                WTcat[d * 40 + t]      = wh;
                WTcat[d * 40 + 16 + t] = (f16)(wv - (float)wh);
                const float nu = -(bt * ktlTT[d * 18 + t] * ig);
                const f16 nuh = (f16)nu;
                UTcat[d * 40 + t]      = nuh;
                UTcat[d * 40 + 16 + t] = (f16)(nu - (float)nuh);
            }
        }
        __syncthreads();   // B6

        // ---- PH7 (v7 Phase A): [P;Q']*Z0 (all waves) + pair matrices (waves 0-3) ----
        {
            const int et = wid & 3;
            const f16* Amh = (wid < 4) ? PhT : QhT;
            const f16* Aml = (wid < 4) ? PlT : QlT;
            const int ar = l15 * 72 + (q4 & 1) * 8;
            const int br = (et * 16 + l15) * 136 + q4 * 8;
            v4f acc = {0.f, 0.f, 0.f, 0.f};
            #pragma unroll
            for (int c = 0; c < 4; ++c){
                const v8h ah = *(const v8h*)(Amh + ar + c * 16);
                const v8h al = *(const v8h*)(Aml + ar + c * 16);
                const v8h bz = *(const v8h*)(ZTcat + br + c * 32);
                acc = __builtin_amdgcn_mfma_f32_16x16x32_f16(ah, bz, acc, 0, 0, 0);
                acc = __builtin_amdgcn_mfma_f32_16x16x32_f16(al, bz, acc, 0, 0, 0);
            }
            float* Rdst = (wid < 4) ? Hs : Ob;
            #pragma unroll
            for (int j = 0; j < 4; ++j)
                Rdst[(q4 * 4 + j) * 68 + et * 16 + l15] = acc[j];

            if (wid < 4){
                const f16* A2h = (wid < 2) ? PhT : QhT;
                const f16* A2l = (wid < 2) ? PlT : QlT;
                const f16* Bp  = (wid & 1) ? Ucat : Wcat;
                const int br2 = l15 * 136 + q4 * 8;
                v4f pacc = {0.f, 0.f, 0.f, 0.f};
                #pragma unroll
                for (int c = 0; c < 4; ++c){
                    const v8h a2h = *(const v8h*)(A2h + ar + c * 16);
                    const v8h a2l = *(const v8h*)(A2l + ar + c * 16);
                    const v8h bw  = *(const v8h*)(Bp + br2 + c * 32);
                    pacc = __builtin_amdgcn_mfma_f32_16x16x32_f16(a2h, bw, pacc, 0, 0, 0);
                    pacc = __builtin_amdgcn_mfma_f32_16x16x32_f16(a2l, bw, pacc, 0, 0, 0);
                }
                if (wid == 1){
                    #pragma unroll
                    for (int j = 0; j < 4; ++j)
                        C2s[(q4 * 4 + j) * 17 + l15] = pacc[j];
                } else {
                    const int mm = (wid == 0) ? 0 : (wid == 2) ? 1 : 2;
                    #pragma unroll
                    for (int j = 0; j < 4; ++j){
                        const int t = q4 * 4 + j, i = l15;
                        float v = ((mm == 0) ? (i < t) : (i <= t)) ? pacc[j] : 0.0f;
                        if (mm == 2) v = -v;
                        const f16 vh = (f16)v;
                        Cmcat[mm * 640 + t * 40 + i] = vh;
                        Cmcat[mm * 640 + t * 40 + 16 + i] = (f16)(v - (float)vh);
                    }
                }
            }
        }
        __syncthreads();   // B7

        // ---- PH8 (v7 Phase C): Hs += SL(C1)*V ; Ob += L(C3)*V ----
        {
            const int et = wid & 3;
            const int mm = (wid < 4) ? 0 : 1;
            float* Rd = (wid < 4) ? Hs : Ob;
            const v8h ac = *(const v8h*)(Cmcat + mm * 640 + l15 * 40 + q4 * 8);
            const v8h bv = *(const v8h*)(VT + (et * 16 + l15) * 24 + (q4 & 1) * 8);
            v4f acc;
            #pragma unroll
            for (int j = 0; j < 4; ++j) acc[j] = Rd[(q4 * 4 + j) * 68 + et * 16 + l15];
            acc = __builtin_amdgcn_mfma_f32_16x16x32_f16(ac, bv, acc, 0, 0, 0);
            #pragma unroll
            for (int j = 0; j < 4; ++j) Rd[(q4 * 4 + j) * 68 + et * 16 + l15] = acc[j];
        }
        __syncthreads();   // B8

        // ---- PH9: solve (wave 0) || stage next + M0 commit (waves 1-7) ----
        if (wid == 0){
            float rhs[SC];
            #pragma unroll
            for (int t = 0; t < SC; ++t) rhs[t] = Hs[t * 68 + l];
            float hreg[SC];
            #pragma unroll
            for (int t = 0; t < SC; ++t){
                float x = rhs[t];
                #pragma unroll
                for (int i = 0; i < SC; ++i)
                    if (i < t) x = fmaf(-C2s[t * 17 + i], hreg[i], x);
                hreg[t] = x;
                const f16 hh = (f16)x;
                HTcat[l * 40 + t] = hh;
                HTcat[l * 40 + 16 + t] = (f16)(x - (float)hh);
            }
        } else {
            if (t0 + SC < TT){
                const int base = tid - 64;
                #pragma unroll
                for (int rep = 0; rep < 2; ++rep){
                    const int ch = base + rep * 448;
                    if (ch < 512){
                        const int tens2 = ch >> 7, rem2 = ch & 127;
                        const int str2 = rem2 >> 3, jj = rem2 & 7;
                        const f16* sgp = (tens2 == 0) ? Qb : (tens2 == 1) ? Kb : (tens2 == 2) ? Vb : Ab;
                        f16* slp = (tens2 == 0) ? tQ : (tens2 == 1) ? tK : (tens2 == 2) ? tV : tA;
                        const uint4 dd0 = *(const uint4*)(sgp + cbase + (size_t)(t0 + SC + str2) * 1024 + jj * 8);
                        *(uint4*)(slp + str2 * 64 + jj * 8) = dd0;
                    }
                }
                if (base < SC) betaT[base] = beta[(size_t)chain * TT + t0 + SC + base];
            }
            // M0 commit: M0 <- gm^16 M0 + Kn^T E Kn  (16 tiles over waves 1-7)
            const float gm16 = gmps[16];
            #pragma unroll
            for (int r = 0; r < 3; ++r){
                const int tile = (wid - 1) + 7 * r;
                if (tile < 16){
                    const int rt = tile >> 2, ct = tile & 3;
                    const int ar = (rt * 16 + l15) * 40 + (q4 & 1) * 8;
                    const int br = (ct * 16 + l15) * 40 + q4 * 8;
                    v4f acc;
                    #pragma unroll
                    for (int j = 0; j < 4; ++j){
                        const int row = rt * 16 + q4 * 4 + j, col = ct * 16 + l15;
                        acc[j] = gm16 * ((float)M0h[row * 72 + col] + (float)M0l[row * 72 + col]);
                    }
                    acc = __builtin_amdgcn_mfma_f32_16x16x32_f16(
                            *(const v8h*)(KnTcat + ar), *(const v8h*)(KnTEcat + br), acc, 0, 0, 0);
                    acc = __builtin_amdgcn_mfma_f32_16x16x32_f16(
                            *(const v8h*)(KnTcat + ar + 16), *(const v8h*)(KnTEcat + br), acc, 0, 0, 0);
                    #pragma unroll
                    for (int j = 0; j < 4; ++j){
                        const int row = rt * 16 + q4 * 4 + j, col = ct * 16 + l15;
                        const float v = acc[j];
                        const f16 vh = (f16)v;
                        M0h[row * 72 + col] = vh;
                        M0l[row * 72 + col] = (f16)(v - (float)vh);
                    }
                }
            }
        }
        __syncthreads();   // B9

        // ---- PH10 (v7 Phase F): O finalize (w0-3) + Z^T commit (all waves) ----
        {
            const int et = wid & 3;
            const int arow = et * 16 + l15;
            const v8h aV  = *(const v8h*)(VT + arow * 24 + (q4 & 1) * 8);
            const v8h aHh = *(const v8h*)(HTcat + arow * 40 + (q4 & 1) * 8);
            const v8h aHl = *(const v8h*)(HTcat + arow * 40 + 16 + (q4 & 1) * 8);

            if (wid < 4){
                const v8h aC = *(const v8h*)(Cmcat + 2 * 640 + l15 * 40 + q4 * 8);
                v4f acc2;
                #pragma unroll
                for (int j = 0; j < 4; ++j) acc2[j] = Ob[(q4 * 4 + j) * 68 + et * 16 + l15];
                acc2 = __builtin_amdgcn_mfma_f32_16x16x32_f16(aC, aHh, acc2, 0, 0, 0);
                acc2 = __builtin_amdgcn_mfma_f32_16x16x32_f16(aC, aHl, acc2, 0, 0, 0);
                #pragma unroll
                for (int j = 0; j < 4; ++j){
                    const int t = q4 * 4 + j;
                    O[cbase + (size_t)(t0 + t) * 1024 + et * 16 + l15] = (f16)acc2[j];
                }
            }

            #pragma unroll
            for (int tt2 = 0; tt2 < 2; ++tt2){
                const int dt = (wid >> 2) * 2 + tt2;
                const v8h bW = *(const v8h*)(WTcat + (dt * 16 + l15) * 40 + q4 * 8);
                const v8h bU = *(const v8h*)(UTcat + (dt * 16 + l15) * 40 + q4 * 8);
                v4f acc;
                #pragma unroll
                for (int j = 0; j < 4; ++j){
                    const int er = et * 16 + q4 * 4 + j;
                    acc[j] = (float)ZTcat[er * 136 + dt * 32 + l15]
                           + (float)ZTcat[er * 136 + dt * 32 + 16 + l15];
                }
                acc = __builtin_amdgcn_mfma_f32_16x16x32_f16(aV,  bW, acc, 0, 0, 0);
                acc = __builtin_amdgcn_mfma_f32_16x16x32_f16(aHh, bU, acc, 0, 0, 0);
                acc = __builtin_amdgcn_mfma_f32_16x16x32_f16(aHl, bU, acc, 0, 0, 0);
                const float gl = GcT[(dt * 16 + l15) * 18 + 15];
                #pragma unroll
                for (int j = 0; j < 4; ++j){
                    const float z = acc[j] * gl;
                    const int er = et * 16 + q4 * 4 + j;
                    const f16 zh = (f16)z;
                    ZTcat[er * 136 + dt * 32 + l15] = zh;
                    ZTcat[er * 136 + dt * 32 + 16 + l15] = (f16)(z - (float)zh);
                }
            }
        }
        // loop-top barrier (B0) separates commit writes / staged raw from next tile
    }
}

// ---------------- workspace layout (bytes), total ~107 MB ----------------
#define OFF_XN    ((size_t)0)                     // 16384*1024 f16 = 32 MB  (later: O)
#define OFF_WCAT  ((size_t)33554432)              // 4*1024*1024 f16 = 8 MB
#define OFF_WOT   ((size_t)41943040)              // 1024*1024 f16  =  2 MB
#define OFF_BETA  ((size_t)44040192)              // 128*2048 f32   =  1 MB
#define OFF_V     ((size_t)45088768)              // 16384*1024 f16 = 32 MB
#define OFF_A     ((size_t)78643200)              // 16384*1024 f16 = 32 MB
#define WS_NEED   ((size_t)112197632)

extern "C" void kernel_launch(void* const* d_in, const int* in_sizes, int n_in,
                              void* d_out, int out_size, void* d_ws, size_t ws_size,
                              hipStream_t stream)
{
    const float* x   = (const float*)d_in[0];
    const float* lng = (const float*)d_in[1];
    const float* lnb = (const float*)d_in[2];
    const float* Wq  = (const float*)d_in[3];
    const float* Wk  = (const float*)d_in[4];
    const float* Wv  = (const float*)d_in[5];
    const float* Wa  = (const float*)d_in[6];
    const float* ba  = (const float*)d_in[7];
    const float* Wb  = (const float*)d_in[8];
    const float* bb  = (const float*)d_in[9];
    const float* rgm = (const float*)d_in[10];
    const float* Wo  = (const float*)d_in[11];
    float* out = (float*)d_out;

    if (ws_size < WS_NEED){
        sentinel_fill<<<(out_size + 255) / 256, 256, 0, stream>>>(out, out_size);
        return;
    }

    char* ws = (char*)d_ws;
    f16*   xn   = (f16*)(ws + OFF_XN);
    f16*   wcat = (f16*)(ws + OFF_WCAT);
    f16*   wot  = (f16*)(ws + OFF_WOT);
    float* betw = (float*)(ws + OFF_BETA);
    f16*   Vbuf = (f16*)(ws + OFF_V);
    f16*   Abuf = (f16*)(ws + OFF_A);
    f16*   Qbuf = (f16*)d_out;                    // 32 MB
    f16*   Kbuf = Qbuf + (size_t)16384 * 1024;    // 32 MB (d_out total = 64 MB)
    f16*   Obuf = xn;                             // reuse xn slot after it's dead

    ln_kernel<<<16384, 256, 0, stream>>>(x, lng, lnb, xn);
    transpose5<<<dim3(32, 32, 5), dim3(32, 8), 0, stream>>>(Wq, Wk, Wv, Wa, Wo, wcat, wot);
    gemm_bt<0><<<dim3(128, 32), 256, 0, stream>>>(xn, wcat, 16384, 4096, 1024,
                                                  ba, nullptr, nullptr, Qbuf, Kbuf, Vbuf, Abuf);
    beta_kernel<<<16384, 256, 0, stream>>>(xn, Wb, bb, betw);
    scan_kernel<<<128, 512, 0, stream>>>(Qbuf, Kbuf, Vbuf, Abuf, betw, rgm, Obuf);
    gemm_bt<1><<<dim3(128, 8), 256, 0, stream>>>(Obuf, wot, 16384, 1024, 1024,
                                                 nullptr, x, out, nullptr, nullptr, nullptr, nullptr);
}